// Round 9
// baseline (336.929 us; speedup 1.0000x reference)
//
#include <hip/hip_runtime.h>

// ---------------- problem constants ----------------
#define NCONS 10000
#define NCOLSN 10000
#define NNODES 20000         // NCONS + NCOLSN
#define NEDGE 200000
#define NETOT 220000         // NEDGE + NNODES self loops
#define NEG_SLOPE 0.2f
#define NSCANB 79            // ceil(NNODES/256)

typedef unsigned short u16;
typedef __attribute__((ext_vector_type(8))) short bf16x8;
typedef __attribute__((ext_vector_type(4))) float f32x4;

__device__ __forceinline__ float bf2f(u16 u) {
  return __uint_as_float(((unsigned int)u) << 16);
}
__device__ __forceinline__ u16 f2bf(float f) {
  unsigned int x = __float_as_uint(f);
  return (u16)((x + 0x7fffu + ((x >> 16) & 1u)) >> 16);
}
__device__ __forceinline__ float lrelu(float v) {
  return v >= 0.f ? v : NEG_SLOPE * v;
}
// async global->LDS, 16 B per lane; LDS dest must be wave-uniform base + lane*16
__device__ __forceinline__ void gl2lds16(const u16* g, u16* l) {
  __builtin_amdgcn_global_load_lds(
      (const __attribute__((address_space(1))) unsigned int*)g,
      (__attribute__((address_space(3))) unsigned int*)l, 16, 0, 0);
}
__device__ __forceinline__ float readlane_f(float v, int j) {
  return __uint_as_float(__builtin_amdgcn_readlane(__float_as_uint(v), j));
}

#define W1N (1024 * 128)
#define W2N (128 * 1024)
#define OWN (128 * 128)
#define EMB0N (NNODES * 128)

// ---------------- fused: layer-0 embed + weight f32->bf16 conversion ----------------
__global__ void prep(const float* __restrict__ cons, const float* __restrict__ cols,
                     const float* __restrict__ nW, const float* __restrict__ nb,
                     const float* __restrict__ cW, const float* __restrict__ cb,
                     const float* __restrict__ W1, const float* __restrict__ W2,
                     const float* __restrict__ oW, u16* __restrict__ emb,
                     u16* __restrict__ Wbf) {
  int idx = blockIdx.x * 256 + threadIdx.x;
  if (idx < EMB0N) {
    int row = idx >> 7, o = idx & 127;
    float acc;
    if (row < NCONS) {
      acc = nb[o];
      #pragma unroll
      for (int k = 0; k < 4; ++k)
        acc += cons[row * 4 + k] * (nW[o * 8 + k] + nW[o * 8 + 4 + k]);
    } else {
      int r = row - NCONS;
      acc = cb[o];
      #pragma unroll
      for (int k = 0; k < 8; ++k)
        acc += cols[r * 8 + k] * (cW[o * 16 + k] + cW[o * 16 + 8 + k]);
    }
    emb[idx] = f2bf(fmaxf(acc, 0.f));
  } else {
    int i = idx - EMB0N;
    if (i >= W1N + W2N + OWN) return;
    float v;
    if (i < W1N) v = W1[i];
    else if (i < W1N + W2N) v = W2[i - W1N];
    else v = oW[i - W1N - W2N];
    Wbf[i] = f2bf(v);
  }
}

// ---------------- CSR build ----------------
__global__ void count_edges(const int* __restrict__ edges, int* __restrict__ counts) {
  int i = blockIdx.x * 256 + threadIdx.x;
  if (i >= NETOT) return;
  int dst = (i < NEDGE) ? edges[NEDGE + i] : (i - NEDGE);
  atomicAdd(&counts[dst], 1);
}

__global__ void scan_a(const int* __restrict__ counts, int* __restrict__ lscan,
                       int* __restrict__ bsum) {
  __shared__ int sh[256];
  int t = threadIdx.x;
  int i = blockIdx.x * 256 + t;
  int v = (i < NNODES) ? counts[i] : 0;
  sh[t] = v;
  __syncthreads();
  for (int d = 1; d < 256; d <<= 1) {
    int add = (t >= d) ? sh[t - d] : 0;
    __syncthreads();
    sh[t] += add;
    __syncthreads();
  }
  lscan[i] = sh[t];
  if (t == 255) bsum[blockIdx.x] = sh[255];
}
__global__ void scan_b(const int* __restrict__ bsum, int* __restrict__ bbase) {
  __shared__ int sh[128];
  int t = threadIdx.x;
  int v = (t < NSCANB) ? bsum[t] : 0;
  sh[t] = v;
  __syncthreads();
  for (int d = 1; d < 128; d <<= 1) {
    int add = (t >= d) ? sh[t - d] : 0;
    __syncthreads();
    sh[t] += add;
    __syncthreads();
  }
  if (t < NSCANB) bbase[t] = sh[t] - v;
}
__global__ void scan_c(const int* __restrict__ lscan, const int* __restrict__ counts,
                       const int* __restrict__ bbase, int* __restrict__ offsets,
                       int* __restrict__ cursor) {
  int t = threadIdx.x;
  int i = blockIdx.x * 256 + t;
  if (i == 0) offsets[0] = 0;
  if (i < NNODES) {
    int incl = lscan[i] + bbase[blockIdx.x];
    offsets[i + 1] = incl;
    cursor[i] = incl - counts[i];
  }
}

__global__ void fill_edges(const int* __restrict__ edges, int* __restrict__ cursor,
                           int* __restrict__ csr_src) {
  int i = blockIdx.x * 256 + threadIdx.x;
  if (i >= NETOT) return;
  int src, dst;
  if (i < NEDGE) { src = edges[i]; dst = edges[NEDGE + i]; }
  else { src = dst = i - NEDGE; }
  int pos = atomicAdd(&cursor[dst], 1);
  csr_src[pos] = src;
}

// ---------------- LDS-staged GEMM (m97 structure): C[M,N] = A[M,K] @ B[N,K]^T ----------------
// 128x128 block tile, BK=32, 256 thr = 4 waves, each wave 64x64 (4x4 MFMA 16x16x32).
// DOTS: fused attention-dot partials -> atomicAdd a_src/a_dst [M, N/128] (h = blockIdx.y)
// HM:   head-major store C[(col>>7)][row][col&127], slice stride NNODES*128
template <bool DOTS, bool HM, bool BIAS, bool OUTF32>
__global__ __launch_bounds__(256) void gemm_bt(const u16* __restrict__ A, const u16* __restrict__ B,
                                               const float* __restrict__ bias, void* __restrict__ Cv,
                                               const float* __restrict__ att_s,
                                               const float* __restrict__ att_d,
                                               float* __restrict__ a_srcO, float* __restrict__ a_dstO,
                                               int M, int N, int K) {
  __shared__ u16 sA[128 * 32];
  __shared__ u16 sB[128 * 32];
  int tid = threadIdx.x;
  int wv = tid >> 6;
  int lane = tid & 63;
  int quad = lane >> 4;
  int l16 = lane & 15;
  int m0 = blockIdx.x * 128;
  int n0g = blockIdx.y * 128;
  int rm = (wv >> 1) * 64;             // wave row base in tile
  int cn = (wv & 1) * 64;              // wave col base in tile

  f32x4 acc[4][4];
  #pragma unroll
  for (int mi = 0; mi < 4; ++mi)
    #pragma unroll
    for (int ni = 0; ni < 4; ++ni) acc[mi][ni] = f32x4{0.f, 0.f, 0.f, 0.f};

  for (int k0 = 0; k0 < K; k0 += 32) {
    // stage A,B tiles (128 rows x 32 cols bf16 = 8192 B each; 2 chunks of 1024 B per wave)
    #pragma unroll
    for (int q = 0; q < 2; ++q) {
      int off = (q * 4 + wv) * 1024 + lane * 16;   // byte offset in tile
      int row = off >> 6;                           // 64 B per row
      int kk = (off & 63) >> 1;                     // u16 col within row
      int rg = m0 + row; if (rg >= M) rg = M - 1;
      gl2lds16(A + (size_t)rg * K + k0 + kk, &sA[off >> 1]);
      gl2lds16(B + (size_t)(n0g + row) * K + k0 + kk, &sB[off >> 1]);
    }
    __syncthreads();
    bf16x8 af[4], bf[4];
    #pragma unroll
    for (int mi = 0; mi < 4; ++mi)
      af[mi] = *(const bf16x8*)&sA[(rm + mi * 16 + l16) * 32 + quad * 8];
    #pragma unroll
    for (int ni = 0; ni < 4; ++ni)
      bf[ni] = *(const bf16x8*)&sB[(cn + ni * 16 + l16) * 32 + quad * 8];
    #pragma unroll
    for (int mi = 0; mi < 4; ++mi)
      #pragma unroll
      for (int ni = 0; ni < 4; ++ni)
        acc[mi][ni] = __builtin_amdgcn_mfma_f32_16x16x32_bf16(af[mi], bf[ni], acc[mi][ni], 0, 0, 0);
    __syncthreads();
  }

  int h = n0g >> 7;                    // one head per 128-col block
  if (DOTS) {
    float av_s[4], av_d[4];
    #pragma unroll
    for (int ni = 0; ni < 4; ++ni) {
      int col = n0g + cn + ni * 16 + l16;
      av_s[ni] = att_s[col];
      av_d[ni] = att_d[col];
    }
    int H = N >> 7;
    #pragma unroll
    for (int mi = 0; mi < 4; ++mi) {
      #pragma unroll
      for (int r = 0; r < 4; ++r) {
        float sp = 0.f, dp = 0.f;
        #pragma unroll
        for (int ni = 0; ni < 4; ++ni) {
          sp += acc[mi][ni][r] * av_s[ni];
          dp += acc[mi][ni][r] * av_d[ni];
        }
        #pragma unroll
        for (int w = 1; w < 16; w <<= 1) {   // reduce over the 16 col-lanes
          sp += __shfl_xor(sp, w, 64);
          dp += __shfl_xor(dp, w, 64);
        }
        int orow = m0 + rm + mi * 16 + quad * 4 + r;
        if (l16 == 0 && orow < M) {
          atomicAdd(&a_srcO[(size_t)orow * H + h], sp);
          atomicAdd(&a_dstO[(size_t)orow * H + h], dp);
        }
      }
    }
  }
  #pragma unroll
  for (int ni = 0; ni < 4; ++ni) {
    int col = n0g + cn + ni * 16 + l16;
    float bv = BIAS ? bias[col] : 0.f;
    #pragma unroll
    for (int mi = 0; mi < 4; ++mi) {
      #pragma unroll
      for (int r = 0; r < 4; ++r) {
        int orow = m0 + rm + mi * 16 + quad * 4 + r;
        if (orow < M) {
          float v = acc[mi][ni][r] + bv;
          if (OUTF32) {
            ((float*)Cv)[(size_t)orow * N + col] = v;
          } else if (HM) {
            ((u16*)Cv)[(size_t)h * ((size_t)NNODES * 128) + (size_t)orow * 128 + (col & 127)] = f2bf(v);
          } else {
            ((u16*)Cv)[(size_t)orow * N + col] = f2bf(v);
          }
        }
      }
    }
  }
}

// ---------------- fused softmax + SpMM layer1 (H=8) ----------------
// wave per (dst, head); h = blockIdx.x & 7 -> XCD affinity on 5 MB head slice.
// Per chunk of <=64 edges: preload srcs into lanes, lane-parallel e + wave softmax
// (flash-style online rescale across chunks), then gather loop with 16 loads in
// flight (readlane -> SGPR index -> scalar-path address). Lane owns channels 2l,2l+1.
__global__ __launch_bounds__(256) void spmm1(const int* __restrict__ offs,
                                             const int* __restrict__ csr_src,
                                             const float* __restrict__ a_src,
                                             const float* __restrict__ a_dst,
                                             const u16* __restrict__ xp1h,
                                             const float* __restrict__ bias,
                                             u16* __restrict__ out) {
  int h = blockIdx.x & 7;
  int wvi = threadIdx.x >> 6;
  int dst = (blockIdx.x >> 3) * 4 + wvi;
  if (dst >= NNODES) return;
  int l = threadIdx.x & 63;
  int off = offs[dst];
  int deg = offs[dst + 1] - off;
  const int* srcs = csr_src + off;
  float ad = a_dst[dst * 8 + h];
  const u16* base = xp1h + (size_t)h * ((size_t)NNODES * 128) + l * 2;
  float m = -1e30f, ssum = 0.f, a0 = 0.f, a1 = 0.f;
  for (int b0 = 0; b0 < deg; b0 += 64) {
    int cnt = deg - b0; if (cnt > 64) cnt = 64;
    int sv = srcs[b0 + (l < cnt ? l : cnt - 1)];     // coalesced preload
    float e = -1e30f;
    if (l < cnt) e = lrelu(a_src[sv * 8 + h] + ad);  // lane-parallel scattered 4B
    float mc = e;
    #pragma unroll
    for (int w = 1; w < 64; w <<= 1) mc = fmaxf(mc, __shfl_xor(mc, w, 64));
    float pex = __expf(e - mc);                      // invalid lanes -> 0
    float sc = pex;
    #pragma unroll
    for (int w = 1; w < 64; w <<= 1) sc += __shfl_xor(sc, w, 64);
    float c0 = 0.f, c1 = 0.f;
    for (int j0 = 0; j0 < cnt; j0 += 16) {
      ushort2 uu[16];
      float ww[16];
      #pragma unroll
      for (int t = 0; t < 16; ++t) {                 // 16 independent gathers in flight
        int j = j0 + t;
        int jc = j < cnt ? j : 0;
        int s = __builtin_amdgcn_readlane(sv, jc);
        float w = readlane_f(pex, jc);
        ww[t] = (j < cnt) ? w : 0.f;
        uu[t] = *(const ushort2*)(base + (size_t)s * 128);
      }
      #pragma unroll
      for (int t = 0; t < 16; ++t) {
        c0 += ww[t] * bf2f(uu[t].x);
        c1 += ww[t] * bf2f(uu[t].y);
      }
    }
    float nm = fmaxf(m, mc);
    float fo = __expf(m - nm), fn = __expf(mc - nm);
    a0 = a0 * fo + c0 * fn;
    a1 = a1 * fo + c1 * fn;
    ssum = ssum * fo + sc * fn;
    m = nm;
  }
  float inv = 1.f / (ssum + 1e-16f);
  int cg = h * 128 + l * 2;
  ushort2 o;
  o.x = f2bf(fmaxf(a0 * inv + bias[cg], 0.f));
  o.y = f2bf(fmaxf(a1 * inv + bias[cg + 1], 0.f));
  *(ushort2*)(out + (size_t)dst * 1024 + cg) = o;
}

// ---------------- fused softmax + SpMM layer2 (H=1, C=128) ----------------
__global__ __launch_bounds__(256) void spmm2(const int* __restrict__ offs,
                                             const int* __restrict__ csr_src,
                                             const float* __restrict__ a_src,
                                             const float* __restrict__ a_dst,
                                             const u16* __restrict__ xp2,
                                             const float* __restrict__ bias,
                                             u16* __restrict__ out) {
  int wvi = threadIdx.x >> 6;
  int dst = blockIdx.x * 4 + wvi;
  if (dst >= NNODES) return;
  int l = threadIdx.x & 63;
  int off = offs[dst];
  int deg = offs[dst + 1] - off;
  const int* srcs = csr_src + off;
  float ad = a_dst[dst];
  const u16* base = xp2 + l * 2;
  float m = -1e30f, ssum = 0.f, a0 = 0.f, a1 = 0.f;
  for (int b0 = 0; b0 < deg; b0 += 64) {
    int cnt = deg - b0; if (cnt > 64) cnt = 64;
    int sv = srcs[b0 + (l < cnt ? l : cnt - 1)];
    float e = -1e30f;
    if (l < cnt) e = lrelu(a_src[sv] + ad);
    float mc = e;
    #pragma unroll
    for (int w = 1; w < 64; w <<= 1) mc = fmaxf(mc, __shfl_xor(mc, w, 64));
    float pex = __expf(e - mc);
    float sc = pex;
    #pragma unroll
    for (int w = 1; w < 64; w <<= 1) sc += __shfl_xor(sc, w, 64);
    float c0 = 0.f, c1 = 0.f;
    for (int j0 = 0; j0 < cnt; j0 += 16) {
      ushort2 uu[16];
      float ww[16];
      #pragma unroll
      for (int t = 0; t < 16; ++t) {
        int j = j0 + t;
        int jc = j < cnt ? j : 0;
        int s = __builtin_amdgcn_readlane(sv, jc);
        float w = readlane_f(pex, jc);
        ww[t] = (j < cnt) ? w : 0.f;
        uu[t] = *(const ushort2*)(base + (size_t)s * 128);
      }
      #pragma unroll
      for (int t = 0; t < 16; ++t) {
        c0 += ww[t] * bf2f(uu[t].x);
        c1 += ww[t] * bf2f(uu[t].y);
      }
    }
    float nm = fmaxf(m, mc);
    float fo = __expf(m - nm), fn = __expf(mc - nm);
    a0 = a0 * fo + c0 * fn;
    a1 = a1 * fo + c1 * fn;
    ssum = ssum * fo + sc * fn;
    m = nm;
  }
  float inv = 1.f / (ssum + 1e-16f);
  int cg = l * 2;
  ushort2 o;
  o.x = f2bf(fmaxf(a0 * inv + bias[cg], 0.f));
  o.y = f2bf(fmaxf(a1 * inv + bias[cg + 1], 0.f));
  *(ushort2*)(out + (size_t)dst * 128 + cg) = o;
}

// ---------------- launch ----------------
extern "C" void kernel_launch(void* const* d_in, const int* in_sizes, int n_in,
                              void* d_out, int out_size, void* d_ws, size_t ws_size,
                              hipStream_t stream) {
  const float* cons    = (const float*)d_in[0];
  const float* cols    = (const float*)d_in[1];
  const float* node_W  = (const float*)d_in[2];
  const float* node_b  = (const float*)d_in[3];
  const float* col_W   = (const float*)d_in[4];
  const float* col_b   = (const float*)d_in[5];
  const float* W1      = (const float*)d_in[6];
  const float* att_s1  = (const float*)d_in[7];
  const float* att_d1  = (const float*)d_in[8];
  const float* b1      = (const float*)d_in[9];
  const float* W2      = (const float*)d_in[10];
  const float* att_s2  = (const float*)d_in[11];
  const float* att_d2  = (const float*)d_in[12];
  const float* b2      = (const float*)d_in[13];
  const float* out_W   = (const float*)d_in[14];
  const float* out_b   = (const float*)d_in[15];
  const int* edges     = (const int*)d_in[16];

  char* p = (char*)d_ws;
  auto alloc = [&](size_t bytes) {
    char* r = p;
    p += (bytes + 255) & ~(size_t)255;
    return r;
  };
  u16* emb0    = (u16*)alloc((size_t)NNODES * 128 * 2);        // bf16
  u16* xp1h    = (u16*)alloc((size_t)8 * NNODES * 128 * 2);    // bf16, head-major slices
  u16* emb2    = (u16*)alloc((size_t)NNODES * 1024 * 2);       // bf16
  u16* xp2     = (u16*)alloc((size_t)NNODES * 128 * 2);        // bf16
  u16* emb3    = (u16*)alloc((size_t)NNODES * 128 * 2);        // bf16
  u16* Wbf     = (u16*)alloc((size_t)(W1N + W2N + OWN) * 2);   // W1|W2|out_W contiguous
  // ---- contiguous zero region: as1, ad1, as2, ad2, counts ----
  float* as1   = (float*)alloc((size_t)NNODES * 8 * 4);        // 640000 B (256-mult)
  float* ad1   = (float*)alloc((size_t)NNODES * 8 * 4);        // 640000 B
  float* as2   = (float*)alloc((size_t)NNODES * 4);            // pads to 80128 B
  float* ad2   = (float*)alloc((size_t)NNODES * 4);            // pads to 80128 B
  int* counts  = (int*)alloc((size_t)NNODES * 4);              // pads to 80128 B
  size_t zspan = (char*)(counts + NNODES) - (char*)as1;
  // ---- end zero region ----
  int* offs    = (int*)alloc((size_t)(NNODES + 1) * 4);
  int* cursor  = (int*)alloc((size_t)NNODES * 4);
  int* csrsrc  = (int*)alloc((size_t)NETOT * 4);
  int* lscan   = (int*)alloc((size_t)NSCANB * 256 * 4);
  int* bsum    = (int*)alloc((size_t)NSCANB * 4);
  int* bbase   = (int*)alloc((size_t)NSCANB * 4);

  u16* W1bf = Wbf;
  u16* W2bf = Wbf + W1N;
  u16* oWbf = Wbf + W1N + W2N;

  hipMemsetAsync(as1, 0, zspan, stream);

  // CSR build
  count_edges<<<(NETOT + 255) / 256, 256, 0, stream>>>(edges, counts);
  scan_a<<<NSCANB, 256, 0, stream>>>(counts, lscan, bsum);
  scan_b<<<1, 128, 0, stream>>>(bsum, bbase);
  scan_c<<<NSCANB, 256, 0, stream>>>(lscan, counts, bbase, offs, cursor);
  fill_edges<<<(NETOT + 255) / 256, 256, 0, stream>>>(edges, cursor, csrsrc);

  // layer 0 embed + weight conversions, fused
  prep<<<(EMB0N + W1N + W2N + OWN + 255) / 256, 256, 0, stream>>>(
      cons, cols, node_W, node_b, col_W, col_b, W1, W2, out_W, emb0, Wbf);

  // GAT layer 1: GEMM (fused dots, head-major out) -> fused softmax+SpMM
  gemm_bt<true, true, false, false><<<dim3((NNODES + 127) / 128, 1024 / 128), 256, 0, stream>>>(
      emb0, W1bf, nullptr, xp1h, att_s1, att_d1, as1, ad1, NNODES, 1024, 128);
  spmm1<<<8 * ((NNODES + 3) / 4), 256, 0, stream>>>(offs, csrsrc, as1, ad1, xp1h, b1, emb2);

  // GAT layer 2: GEMM (fused dots) -> fused softmax+SpMM
  gemm_bt<true, false, false, false><<<dim3((NNODES + 127) / 128, 1), 256, 0, stream>>>(
      emb2, W2bf, nullptr, xp2, att_s2, att_d2, as2, ad2, NNODES, 128, 1024);
  spmm2<<<(NNODES + 3) / 4, 256, 0, stream>>>(offs, csrsrc, as2, ad2, xp2, b2, emb3);

  // output projection: rows 10000..19999, f32 out with bias
  gemm_bt<false, false, true, true><<<dim3((NCOLSN + 127) / 128, 1), 256, 0, stream>>>(
      emb3 + (size_t)NCONS * 128, oWbf, out_b, d_out, nullptr, nullptr, nullptr, nullptr,
      NCOLSN, 128, 128);
}

// Round 10
// 326.216 us; speedup vs baseline: 1.0328x; 1.0328x over previous
//
#include <hip/hip_runtime.h>

// ---------------- problem constants ----------------
#define NCONS 10000
#define NCOLSN 10000
#define NNODES 20000         // NCONS + NCOLSN
#define NEDGE 200000
#define NETOT 220000         // NEDGE + NNODES self loops
#define NEG_SLOPE 0.2f
#define NSCANB 79            // ceil(NNODES/256)

typedef unsigned short u16;
typedef __attribute__((ext_vector_type(8))) short bf16x8;
typedef __attribute__((ext_vector_type(4))) float f32x4;

__device__ __forceinline__ float bf2f(u16 u) {
  return __uint_as_float(((unsigned int)u) << 16);
}
__device__ __forceinline__ u16 f2bf(float f) {
  unsigned int x = __float_as_uint(f);
  return (u16)((x + 0x7fffu + ((x >> 16) & 1u)) >> 16);
}
__device__ __forceinline__ float lrelu(float v) {
  return v >= 0.f ? v : NEG_SLOPE * v;
}
// async global->LDS, 16 B per lane; LDS dest must be wave-uniform base + lane*16
__device__ __forceinline__ void gl2lds16(const u16* g, u16* l) {
  __builtin_amdgcn_global_load_lds(
      (const __attribute__((address_space(1))) unsigned int*)g,
      (__attribute__((address_space(3))) unsigned int*)l, 16, 0, 0);
}
__device__ __forceinline__ float readlane_f(float v, int j) {
  return __uint_as_float(__builtin_amdgcn_readlane(__float_as_uint(v), j));
}

#define W1N (1024 * 128)
#define W2N (128 * 1024)
#define OWN (128 * 128)
#define EMB0N (NNODES * 128)

// ---------------- fused: layer-0 embed + weight f32->bf16 conversion ----------------
__global__ void prep(const float* __restrict__ cons, const float* __restrict__ cols,
                     const float* __restrict__ nW, const float* __restrict__ nb,
                     const float* __restrict__ cW, const float* __restrict__ cb,
                     const float* __restrict__ W1, const float* __restrict__ W2,
                     const float* __restrict__ oW, u16* __restrict__ emb,
                     u16* __restrict__ Wbf) {
  int idx = blockIdx.x * 256 + threadIdx.x;
  if (idx < EMB0N) {
    int row = idx >> 7, o = idx & 127;
    float acc;
    if (row < NCONS) {
      acc = nb[o];
      #pragma unroll
      for (int k = 0; k < 4; ++k)
        acc += cons[row * 4 + k] * (nW[o * 8 + k] + nW[o * 8 + 4 + k]);
    } else {
      int r = row - NCONS;
      acc = cb[o];
      #pragma unroll
      for (int k = 0; k < 8; ++k)
        acc += cols[r * 8 + k] * (cW[o * 16 + k] + cW[o * 16 + 8 + k]);
    }
    emb[idx] = f2bf(fmaxf(acc, 0.f));
  } else {
    int i = idx - EMB0N;
    if (i >= W1N + W2N + OWN) return;
    float v;
    if (i < W1N) v = W1[i];
    else if (i < W1N + W2N) v = W2[i - W1N];
    else v = oW[i - W1N - W2N];
    Wbf[i] = f2bf(v);
  }
}

// ---------------- CSR build ----------------
__global__ void count_edges(const int* __restrict__ edges, int* __restrict__ counts) {
  int i = blockIdx.x * 256 + threadIdx.x;
  if (i >= NETOT) return;
  int dst = (i < NEDGE) ? edges[NEDGE + i] : (i - NEDGE);
  atomicAdd(&counts[dst], 1);
}

__global__ void scan_a(const int* __restrict__ counts, int* __restrict__ lscan,
                       int* __restrict__ bsum) {
  __shared__ int sh[256];
  int t = threadIdx.x;
  int i = blockIdx.x * 256 + t;
  int v = (i < NNODES) ? counts[i] : 0;
  sh[t] = v;
  __syncthreads();
  for (int d = 1; d < 256; d <<= 1) {
    int add = (t >= d) ? sh[t - d] : 0;
    __syncthreads();
    sh[t] += add;
    __syncthreads();
  }
  lscan[i] = sh[t];
  if (t == 255) bsum[blockIdx.x] = sh[255];
}
__global__ void scan_b(const int* __restrict__ bsum, int* __restrict__ bbase) {
  __shared__ int sh[128];
  int t = threadIdx.x;
  int v = (t < NSCANB) ? bsum[t] : 0;
  sh[t] = v;
  __syncthreads();
  for (int d = 1; d < 128; d <<= 1) {
    int add = (t >= d) ? sh[t - d] : 0;
    __syncthreads();
    sh[t] += add;
    __syncthreads();
  }
  if (t < NSCANB) bbase[t] = sh[t] - v;
}
__global__ void scan_c(const int* __restrict__ lscan, const int* __restrict__ counts,
                       const int* __restrict__ bbase, int* __restrict__ offsets,
                       int* __restrict__ cursor) {
  int t = threadIdx.x;
  int i = blockIdx.x * 256 + t;
  if (i == 0) offsets[0] = 0;
  if (i < NNODES) {
    int incl = lscan[i] + bbase[blockIdx.x];
    offsets[i + 1] = incl;
    cursor[i] = incl - counts[i];
  }
}

__global__ void fill_edges(const int* __restrict__ edges, int* __restrict__ cursor,
                           int* __restrict__ csr_src) {
  int i = blockIdx.x * 256 + threadIdx.x;
  if (i >= NETOT) return;
  int src, dst;
  if (i < NEDGE) { src = edges[i]; dst = edges[NEDGE + i]; }
  else { src = dst = i - NEDGE; }
  int pos = atomicAdd(&cursor[dst], 1);
  csr_src[pos] = src;
}

// ---------------- LDS-staged GEMM (m97 structure): C[M,N] = A[M,K] @ B[N,K]^T ----------------
// 128x128 block tile, BK=32, 256 thr = 4 waves, each wave 64x64 (4x4 MFMA 16x16x32).
// DOTS: fused attention-dot partials -> atomicAdd a_src/a_dst [M, N/128] (h = blockIdx.y)
// HM:   head-major store C[(col>>7)][row][col&127], slice stride NNODES*128
template <bool DOTS, bool HM, bool BIAS, bool OUTF32>
__global__ __launch_bounds__(256) void gemm_bt(const u16* __restrict__ A, const u16* __restrict__ B,
                                               const float* __restrict__ bias, void* __restrict__ Cv,
                                               const float* __restrict__ att_s,
                                               const float* __restrict__ att_d,
                                               float* __restrict__ a_srcO, float* __restrict__ a_dstO,
                                               int M, int N, int K) {
  __shared__ u16 sA[128 * 32];
  __shared__ u16 sB[128 * 32];
  int tid = threadIdx.x;
  int wv = tid >> 6;
  int lane = tid & 63;
  int quad = lane >> 4;
  int l16 = lane & 15;
  int m0 = blockIdx.x * 128;
  int n0g = blockIdx.y * 128;
  int rm = (wv >> 1) * 64;             // wave row base in tile
  int cn = (wv & 1) * 64;              // wave col base in tile

  f32x4 acc[4][4];
  #pragma unroll
  for (int mi = 0; mi < 4; ++mi)
    #pragma unroll
    for (int ni = 0; ni < 4; ++ni) acc[mi][ni] = f32x4{0.f, 0.f, 0.f, 0.f};

  for (int k0 = 0; k0 < K; k0 += 32) {
    // stage A,B tiles (128 rows x 32 cols bf16 = 8192 B each; 2 chunks of 1024 B per wave)
    #pragma unroll
    for (int q = 0; q < 2; ++q) {
      int off = (q * 4 + wv) * 1024 + lane * 16;   // byte offset in tile
      int row = off >> 6;                           // 64 B per row
      int kk = (off & 63) >> 1;                     // u16 col within row
      int rg = m0 + row; if (rg >= M) rg = M - 1;
      gl2lds16(A + (size_t)rg * K + k0 + kk, &sA[off >> 1]);
      gl2lds16(B + (size_t)(n0g + row) * K + k0 + kk, &sB[off >> 1]);
    }
    __syncthreads();
    bf16x8 af[4], bf[4];
    #pragma unroll
    for (int mi = 0; mi < 4; ++mi)
      af[mi] = *(const bf16x8*)&sA[(rm + mi * 16 + l16) * 32 + quad * 8];
    #pragma unroll
    for (int ni = 0; ni < 4; ++ni)
      bf[ni] = *(const bf16x8*)&sB[(cn + ni * 16 + l16) * 32 + quad * 8];
    #pragma unroll
    for (int mi = 0; mi < 4; ++mi)
      #pragma unroll
      for (int ni = 0; ni < 4; ++ni)
        acc[mi][ni] = __builtin_amdgcn_mfma_f32_16x16x32_bf16(af[mi], bf[ni], acc[mi][ni], 0, 0, 0);
    __syncthreads();
  }

  int h = n0g >> 7;                    // one head per 128-col block
  if (DOTS) {
    float av_s[4], av_d[4];
    #pragma unroll
    for (int ni = 0; ni < 4; ++ni) {
      int col = n0g + cn + ni * 16 + l16;
      av_s[ni] = att_s[col];
      av_d[ni] = att_d[col];
    }
    int H = N >> 7;
    #pragma unroll
    for (int mi = 0; mi < 4; ++mi) {
      #pragma unroll
      for (int r = 0; r < 4; ++r) {
        float sp = 0.f, dp = 0.f;
        #pragma unroll
        for (int ni = 0; ni < 4; ++ni) {
          sp += acc[mi][ni][r] * av_s[ni];
          dp += acc[mi][ni][r] * av_d[ni];
        }
        #pragma unroll
        for (int w = 1; w < 16; w <<= 1) {   // reduce over the 16 col-lanes
          sp += __shfl_xor(sp, w, 64);
          dp += __shfl_xor(dp, w, 64);
        }
        int orow = m0 + rm + mi * 16 + quad * 4 + r;
        if (l16 == 0 && orow < M) {
          atomicAdd(&a_srcO[(size_t)orow * H + h], sp);
          atomicAdd(&a_dstO[(size_t)orow * H + h], dp);
        }
      }
    }
  }
  #pragma unroll
  for (int ni = 0; ni < 4; ++ni) {
    int col = n0g + cn + ni * 16 + l16;
    float bv = BIAS ? bias[col] : 0.f;
    #pragma unroll
    for (int mi = 0; mi < 4; ++mi) {
      #pragma unroll
      for (int r = 0; r < 4; ++r) {
        int orow = m0 + rm + mi * 16 + quad * 4 + r;
        if (orow < M) {
          float v = acc[mi][ni][r] + bv;
          if (OUTF32) {
            ((float*)Cv)[(size_t)orow * N + col] = v;
          } else if (HM) {
            ((u16*)Cv)[(size_t)h * ((size_t)NNODES * 128) + (size_t)orow * 128 + (col & 127)] = f2bf(v);
          } else {
            ((u16*)Cv)[(size_t)orow * N + col] = f2bf(v);
          }
        }
      }
    }
  }
}

// ---------------- alpha layer1 (H=8): head-major out [8][NETOT] ----------------
// one wave per dst; lane = i*8+h: one wave does softmax for all 8 heads.
__global__ __launch_bounds__(256) void alpha1_k(const int* __restrict__ offs,
                                                const int* __restrict__ csr_src,
                                                const float* __restrict__ a_src,
                                                const float* __restrict__ a_dst,
                                                float* __restrict__ alpha) {
  int wv = threadIdx.x >> 6;
  int dst = blockIdx.x * 4 + wv;
  if (dst >= NNODES) return;
  int l = threadIdx.x & 63;
  int h = l & 7, i = l >> 3;
  int off = offs[dst];
  int deg = offs[dst + 1] - off;
  const int* srcs = csr_src + off;
  float ad = a_dst[dst * 8 + h];
  float m = -1e30f, ssum = 0.f;
  float* out = alpha + (size_t)h * NETOT + off;
  if (deg <= 64) {
    int sl = srcs[l < deg ? l : deg - 1];       // coalesced preload
    float ev[8];
    #pragma unroll
    for (int t = 0; t < 8; ++t) {
      int jj = i + t * 8;
      float e = -1e30f;
      if (jj < deg) {
        int s = __builtin_amdgcn_readlane(sl, jj);
        e = lrelu(a_src[s * 8 + h] + ad);       // 8 h-lanes share s: 32-B segment
      }
      ev[t] = e;
      float nm = fmaxf(m, e);
      ssum = ssum * __expf(m - nm) + ((jj < deg) ? __expf(e - nm) : 0.f);
      m = nm;
    }
    #pragma unroll
    for (int w = 8; w < 64; w <<= 1) {          // reduce over i (lane bits 3..5)
      float om = __shfl_xor(m, w, 64);
      float os = __shfl_xor(ssum, w, 64);
      float nm = fmaxf(m, om);
      ssum = ssum * __expf(m - nm) + os * __expf(om - nm);
      m = nm;
    }
    float inv = 1.f / (ssum + 1e-16f);
    #pragma unroll
    for (int t = 0; t < 8; ++t) {
      int jj = i + t * 8;
      if (jj < deg) out[jj] = __expf(ev[t] - m) * inv;
    }
  } else {
    for (int j = i; j < deg; j += 8) {
      int s = srcs[j];
      float e = lrelu(a_src[s * 8 + h] + ad);
      float nm = fmaxf(m, e);
      ssum = ssum * __expf(m - nm) + __expf(e - nm);
      m = nm;
    }
    #pragma unroll
    for (int w = 8; w < 64; w <<= 1) {
      float om = __shfl_xor(m, w, 64);
      float os = __shfl_xor(ssum, w, 64);
      float nm = fmaxf(m, om);
      ssum = ssum * __expf(m - nm) + os * __expf(om - nm);
      m = nm;
    }
    float inv = 1.f / (ssum + 1e-16f);
    for (int j = i; j < deg; j += 8) {
      int s = srcs[j];
      float e = lrelu(a_src[s * 8 + h] + ad);
      out[j] = __expf(e - m) * inv;
    }
  }
}

// ---------------- alpha layer2 (H=1): only dst in [NCONS, NNODES) ----------------
__global__ __launch_bounds__(256) void alpha2_k(const int* __restrict__ offs,
                                                const int* __restrict__ csr_src,
                                                const float* __restrict__ a_src,
                                                const float* __restrict__ a_dst,
                                                float* __restrict__ alpha) {
  int wv = threadIdx.x >> 6;
  int dst = NCONS + blockIdx.x * 4 + wv;
  if (dst >= NNODES) return;
  int l = threadIdx.x & 63;
  int off = offs[dst];
  int deg = offs[dst + 1] - off;
  float ad = a_dst[dst];
  if (deg <= 64) {
    float e = -1e30f;
    if (l < deg) e = lrelu(a_src[csr_src[off + l]] + ad);
    float m = e;
    #pragma unroll
    for (int w = 1; w < 64; w <<= 1) m = fmaxf(m, __shfl_xor(m, w, 64));
    float p = (l < deg) ? __expf(e - m) : 0.f;
    float ssum = p;
    #pragma unroll
    for (int w = 1; w < 64; w <<= 1) ssum += __shfl_xor(ssum, w, 64);
    float inv = 1.f / (ssum + 1e-16f);
    if (l < deg) alpha[off + l] = p * inv;
  } else {
    float m = -1e30f, ssum = 0.f;
    for (int j = l; j < deg; j += 64) {
      float e = lrelu(a_src[csr_src[off + j]] + ad);
      float nm = fmaxf(m, e);
      ssum = ssum * __expf(m - nm) + __expf(e - nm);
      m = nm;
    }
    #pragma unroll
    for (int w = 1; w < 64; w <<= 1) {
      float om = __shfl_xor(m, w, 64);
      float os = __shfl_xor(ssum, w, 64);
      float nm = fmaxf(m, om);
      ssum = ssum * __expf(m - nm) + os * __expf(om - nm);
      m = nm;
    }
    float inv = 1.f / (ssum + 1e-16f);
    for (int j = l; j < deg; j += 64) {
      float e = lrelu(a_src[csr_src[off + j]] + ad);
      alpha[off + j] = __expf(e - m) * inv;
    }
  }
}

// ---------------- SpMM layer1: head-sliced xp1h, head-major alpha, 16-deep gather ------------
// wave per (dst, head); h = blockIdx.x & 7 -> XCD affinity on 5 MB head slice.
// srcs+alpha preloaded coalesced into lanes; readlane -> SGPR index -> scalar-path address.
// 16 independent gathers in flight per batch. Lane owns channels 2l,2l+1.
__global__ __launch_bounds__(256) void spmm1(const int* __restrict__ offs,
                                             const int* __restrict__ csr_src,
                                             const float* __restrict__ alp,
                                             const u16* __restrict__ xp1h,
                                             const float* __restrict__ bias,
                                             u16* __restrict__ out) {
  int h = blockIdx.x & 7;
  int wvi = threadIdx.x >> 6;
  int dst = (blockIdx.x >> 3) * 4 + wvi;
  if (dst >= NNODES) return;
  int l = threadIdx.x & 63;
  int off = offs[dst];
  int deg = offs[dst + 1] - off;
  const int* srcs = csr_src + off;
  const float* alb = alp + (size_t)h * NETOT + off;
  const u16* base = xp1h + (size_t)h * ((size_t)NNODES * 128) + l * 2;
  float a0 = 0.f, a1 = 0.f;
  for (int b0 = 0; b0 < deg; b0 += 64) {
    int cnt = deg - b0; if (cnt > 64) cnt = 64;
    int sv = srcs[b0 + (l < cnt ? l : cnt - 1)];      // coalesced preload
    float av = (l < cnt) ? alb[b0 + l] : 0.f;         // coalesced preload
    for (int j0 = 0; j0 < cnt; j0 += 16) {
      ushort2 uu[16];
      float ww[16];
      #pragma unroll
      for (int t = 0; t < 16; ++t) {                  // 16 independent gathers in flight
        int j = j0 + t;
        int jc = j < cnt ? j : 0;
        int s = __builtin_amdgcn_readlane(sv, jc);    // SGPR
        float w = readlane_f(av, jc);                 // SGPR
        ww[t] = (j < cnt) ? w : 0.f;
        uu[t] = *(const ushort2*)(base + (size_t)s * 128);
      }
      #pragma unroll
      for (int t = 0; t < 16; ++t) {
        a0 += ww[t] * bf2f(uu[t].x);
        a1 += ww[t] * bf2f(uu[t].y);
      }
    }
  }
  int cg = h * 128 + l * 2;
  ushort2 o;
  o.x = f2bf(fmaxf(a0 + bias[cg], 0.f));
  o.y = f2bf(fmaxf(a1 + bias[cg + 1], 0.f));
  *(ushort2*)(out + (size_t)dst * 1024 + cg) = o;
}

// ---------------- SpMM layer2 (H=1): only dst in [NCONS, NNODES) ----------------
__global__ __launch_bounds__(256) void spmm2(const int* __restrict__ offs,
                                             const int* __restrict__ csr_src,
                                             const float* __restrict__ alpha,
                                             const u16* __restrict__ xp2,
                                             const float* __restrict__ bias,
                                             u16* __restrict__ out) {
  int wvi = threadIdx.x >> 6;
  int dst = NCONS + blockIdx.x * 4 + wvi;
  if (dst >= NNODES) return;
  int l = threadIdx.x & 63;
  int off = offs[dst];
  int deg = offs[dst + 1] - off;
  const int* srcs = csr_src + off;
  const float* al = alpha + off;
  const u16* base = xp2 + l * 2;
  float a0 = 0.f, a1 = 0.f;
  for (int b0 = 0; b0 < deg; b0 += 64) {
    int cnt = deg - b0; if (cnt > 64) cnt = 64;
    int sv = srcs[b0 + (l < cnt ? l : cnt - 1)];
    float av = (l < cnt) ? al[b0 + l] : 0.f;
    for (int j0 = 0; j0 < cnt; j0 += 16) {
      ushort2 uu[16];
      float ww[16];
      #pragma unroll
      for (int t = 0; t < 16; ++t) {
        int j = j0 + t;
        int jc = j < cnt ? j : 0;
        int s = __builtin_amdgcn_readlane(sv, jc);
        float w = readlane_f(av, jc);
        ww[t] = (j < cnt) ? w : 0.f;
        uu[t] = *(const ushort2*)(base + (size_t)s * 128);
      }
      #pragma unroll
      for (int t = 0; t < 16; ++t) {
        a0 += ww[t] * bf2f(uu[t].x);
        a1 += ww[t] * bf2f(uu[t].y);
      }
    }
  }
  int cg = l * 2;
  ushort2 o;
  o.x = f2bf(fmaxf(a0 + bias[cg], 0.f));
  o.y = f2bf(fmaxf(a1 + bias[cg + 1], 0.f));
  *(ushort2*)(out + (size_t)dst * 128 + cg) = o;
}

// ---------------- launch ----------------
extern "C" void kernel_launch(void* const* d_in, const int* in_sizes, int n_in,
                              void* d_out, int out_size, void* d_ws, size_t ws_size,
                              hipStream_t stream) {
  const float* cons    = (const float*)d_in[0];
  const float* cols    = (const float*)d_in[1];
  const float* node_W  = (const float*)d_in[2];
  const float* node_b  = (const float*)d_in[3];
  const float* col_W   = (const float*)d_in[4];
  const float* col_b   = (const float*)d_in[5];
  const float* W1      = (const float*)d_in[6];
  const float* att_s1  = (const float*)d_in[7];
  const float* att_d1  = (const float*)d_in[8];
  const float* b1      = (const float*)d_in[9];
  const float* W2      = (const float*)d_in[10];
  const float* att_s2  = (const float*)d_in[11];
  const float* att_d2  = (const float*)d_in[12];
  const float* b2      = (const float*)d_in[13];
  const float* out_W   = (const float*)d_in[14];
  const float* out_b   = (const float*)d_in[15];
  const int* edges     = (const int*)d_in[16];

  char* p = (char*)d_ws;
  auto alloc = [&](size_t bytes) {
    char* r = p;
    p += (bytes + 255) & ~(size_t)255;
    return r;
  };
  u16* emb0    = (u16*)alloc((size_t)NNODES * 128 * 2);        // bf16
  u16* xp1h    = (u16*)alloc((size_t)8 * NNODES * 128 * 2);    // bf16, head-major slices
  u16* emb2    = (u16*)alloc((size_t)NNODES * 1024 * 2);       // bf16
  u16* xp2     = (u16*)alloc((size_t)NNODES * 128 * 2);        // bf16
  u16* emb3    = (u16*)alloc((size_t)NNODES * 128 * 2);        // bf16
  u16* Wbf     = (u16*)alloc((size_t)(W1N + W2N + OWN) * 2);   // W1|W2|out_W contiguous
  // ---- contiguous zero region: as1, ad1, as2, ad2, counts ----
  float* as1   = (float*)alloc((size_t)NNODES * 8 * 4);        // 640000 B (256-mult)
  float* ad1   = (float*)alloc((size_t)NNODES * 8 * 4);        // 640000 B
  float* as2   = (float*)alloc((size_t)NNODES * 4);            // pads to 80128 B
  float* ad2   = (float*)alloc((size_t)NNODES * 4);            // pads to 80128 B
  int* counts  = (int*)alloc((size_t)NNODES * 4);              // pads to 80128 B
  size_t zspan = (char*)(counts + NNODES) - (char*)as1;
  // ---- end zero region ----
  float* alp1  = (float*)alloc((size_t)8 * NETOT * 4);         // head-major [8][NETOT]
  float* alp2  = (float*)alloc((size_t)NETOT * 4);
  int* offs    = (int*)alloc((size_t)(NNODES + 1) * 4);
  int* cursor  = (int*)alloc((size_t)NNODES * 4);
  int* csrsrc  = (int*)alloc((size_t)NETOT * 4);
  int* lscan   = (int*)alloc((size_t)NSCANB * 256 * 4);
  int* bsum    = (int*)alloc((size_t)NSCANB * 4);
  int* bbase   = (int*)alloc((size_t)NSCANB * 4);

  u16* W1bf = Wbf;
  u16* W2bf = Wbf + W1N;
  u16* oWbf = Wbf + W1N + W2N;

  hipMemsetAsync(as1, 0, zspan, stream);

  // CSR build
  count_edges<<<(NETOT + 255) / 256, 256, 0, stream>>>(edges, counts);
  scan_a<<<NSCANB, 256, 0, stream>>>(counts, lscan, bsum);
  scan_b<<<1, 128, 0, stream>>>(bsum, bbase);
  scan_c<<<NSCANB, 256, 0, stream>>>(lscan, counts, bbase, offs, cursor);
  fill_edges<<<(NETOT + 255) / 256, 256, 0, stream>>>(edges, cursor, csrsrc);

  // layer 0 embed + weight conversions, fused
  prep<<<(EMB0N + W1N + W2N + OWN + 255) / 256, 256, 0, stream>>>(
      cons, cols, node_W, node_b, col_W, col_b, W1, W2, out_W, emb0, Wbf);

  // GAT layer 1: GEMM (fused dots, head-major out) -> alpha (head-major) -> SpMM
  gemm_bt<true, true, false, false><<<dim3((NNODES + 127) / 128, 1024 / 128), 256, 0, stream>>>(
      emb0, W1bf, nullptr, xp1h, att_s1, att_d1, as1, ad1, NNODES, 1024, 128);
  alpha1_k<<<(NNODES + 3) / 4, 256, 0, stream>>>(offs, csrsrc, as1, ad1, alp1);
  spmm1<<<8 * ((NNODES + 3) / 4), 256, 0, stream>>>(offs, csrsrc, alp1, xp1h, b1, emb2);

  // GAT layer 2: GEMM (fused dots) -> alpha -> SpMM (only dst >= NCONS needed)
  gemm_bt<true, false, false, false><<<dim3((NNODES + 127) / 128, 1), 256, 0, stream>>>(
      emb2, W2bf, nullptr, xp2, att_s2, att_d2, as2, ad2, NNODES, 128, 1024);
  alpha2_k<<<(NCOLSN + 3) / 4, 256, 0, stream>>>(offs, csrsrc, as2, ad2, alp2);
  spmm2<<<(NCOLSN + 3) / 4, 256, 0, stream>>>(offs, csrsrc, alp2, xp2, b2, emb3);

  // output projection: rows 10000..19999, f32 out with bias
  gemm_bt<false, false, true, true><<<dim3((NCOLSN + 127) / 128, 1), 256, 0, stream>>>(
      emb3 + (size_t)NCONS * 128, oWbf, out_b, d_out, nullptr, nullptr, nullptr, nullptr,
      NCOLSN, 128, 128);
}

// Round 11
// 319.222 us; speedup vs baseline: 1.0555x; 1.0219x over previous
//
#include <hip/hip_runtime.h>

// ---------------- problem constants ----------------
#define NCONS 10000
#define NCOLSN 10000
#define NNODES 20000         // NCONS + NCOLSN
#define NEDGE 200000
#define NETOT 220000         // NEDGE + NNODES self loops
#define NEG_SLOPE 0.2f
#define NSCANB 79            // ceil(NNODES/256)

typedef unsigned short u16;
typedef __attribute__((ext_vector_type(8))) short bf16x8;
typedef __attribute__((ext_vector_type(4))) float f32x4;

__device__ __forceinline__ float bf2f(u16 u) {
  return __uint_as_float(((unsigned int)u) << 16);
}
__device__ __forceinline__ u16 f2bf(float f) {
  unsigned int x = __float_as_uint(f);
  return (u16)((x + 0x7fffu + ((x >> 16) & 1u)) >> 16);
}
__device__ __forceinline__ float lrelu(float v) {
  return v >= 0.f ? v : NEG_SLOPE * v;
}
// async global->LDS, 16 B per lane; LDS dest must be wave-uniform base + lane*16
__device__ __forceinline__ void gl2lds16(const u16* g, u16* l) {
  __builtin_amdgcn_global_load_lds(
      (const __attribute__((address_space(1))) unsigned int*)g,
      (__attribute__((address_space(3))) unsigned int*)l, 16, 0, 0);
}
__device__ __forceinline__ float readlane_f(float v, int j) {
  return __uint_as_float(__builtin_amdgcn_readlane(__float_as_uint(v), j));
}

#define W1N (1024 * 128)
#define W2N (128 * 1024)
#define OWN (128 * 128)
#define EMB0N (NNODES * 128)

// ---------------- fused: layer-0 embed + weight f32->bf16 conversion ----------------
__global__ void prep(const float* __restrict__ cons, const float* __restrict__ cols,
                     const float* __restrict__ nW, const float* __restrict__ nb,
                     const float* __restrict__ cW, const float* __restrict__ cb,
                     const float* __restrict__ W1, const float* __restrict__ W2,
                     const float* __restrict__ oW, u16* __restrict__ emb,
                     u16* __restrict__ Wbf) {
  int idx = blockIdx.x * 256 + threadIdx.x;
  if (idx < EMB0N) {
    int row = idx >> 7, o = idx & 127;
    float acc;
    if (row < NCONS) {
      acc = nb[o];
      #pragma unroll
      for (int k = 0; k < 4; ++k)
        acc += cons[row * 4 + k] * (nW[o * 8 + k] + nW[o * 8 + 4 + k]);
    } else {
      int r = row - NCONS;
      acc = cb[o];
      #pragma unroll
      for (int k = 0; k < 8; ++k)
        acc += cols[r * 8 + k] * (cW[o * 16 + k] + cW[o * 16 + 8 + k]);
    }
    emb[idx] = f2bf(fmaxf(acc, 0.f));
  } else {
    int i = idx - EMB0N;
    if (i >= W1N + W2N + OWN) return;
    float v;
    if (i < W1N) v = W1[i];
    else if (i < W1N + W2N) v = W2[i - W1N];
    else v = oW[i - W1N - W2N];
    Wbf[i] = f2bf(v);
  }
}

// ---------------- CSR build ----------------
__global__ void count_edges(const int* __restrict__ edges, int* __restrict__ counts) {
  int i = blockIdx.x * 256 + threadIdx.x;
  if (i >= NETOT) return;
  int dst = (i < NEDGE) ? edges[NEDGE + i] : (i - NEDGE);
  atomicAdd(&counts[dst], 1);
}

__global__ void scan_a(const int* __restrict__ counts, int* __restrict__ lscan,
                       int* __restrict__ bsum) {
  __shared__ int sh[256];
  int t = threadIdx.x;
  int i = blockIdx.x * 256 + t;
  int v = (i < NNODES) ? counts[i] : 0;
  sh[t] = v;
  __syncthreads();
  for (int d = 1; d < 256; d <<= 1) {
    int add = (t >= d) ? sh[t - d] : 0;
    __syncthreads();
    sh[t] += add;
    __syncthreads();
  }
  lscan[i] = sh[t];
  if (t == 255) bsum[blockIdx.x] = sh[255];
}
__global__ void scan_b(const int* __restrict__ bsum, int* __restrict__ bbase) {
  __shared__ int sh[128];
  int t = threadIdx.x;
  int v = (t < NSCANB) ? bsum[t] : 0;
  sh[t] = v;
  __syncthreads();
  for (int d = 1; d < 128; d <<= 1) {
    int add = (t >= d) ? sh[t - d] : 0;
    __syncthreads();
    sh[t] += add;
    __syncthreads();
  }
  if (t < NSCANB) bbase[t] = sh[t] - v;
}
__global__ void scan_c(const int* __restrict__ lscan, const int* __restrict__ counts,
                       const int* __restrict__ bbase, int* __restrict__ offsets,
                       int* __restrict__ cursor) {
  int t = threadIdx.x;
  int i = blockIdx.x * 256 + t;
  if (i == 0) offsets[0] = 0;
  if (i < NNODES) {
    int incl = lscan[i] + bbase[blockIdx.x];
    offsets[i + 1] = incl;
    cursor[i] = incl - counts[i];
  }
}

__global__ void fill_edges(const int* __restrict__ edges, int* __restrict__ cursor,
                           int* __restrict__ csr_src) {
  int i = blockIdx.x * 256 + threadIdx.x;
  if (i >= NETOT) return;
  int src, dst;
  if (i < NEDGE) { src = edges[i]; dst = edges[NEDGE + i]; }
  else { src = dst = i - NEDGE; }
  int pos = atomicAdd(&cursor[dst], 1);
  csr_src[pos] = src;
}

// ---------------- LDS-staged GEMM (m97 structure): C[M,N] = A[M,K] @ B[N,K]^T ----------------
// 128x128 block tile, BK=32, 256 thr = 4 waves, each wave 64x64 (4x4 MFMA 16x16x32).
// DOTS: fused attention-dot partials -> atomicAdd a_src/a_dst [M, N/128] (h = blockIdx.y)
// HM:   head-major store C[(col>>7)][row][col&127], slice stride NNODES*128
template <bool DOTS, bool HM, bool BIAS, bool OUTF32>
__global__ __launch_bounds__(256) void gemm_bt(const u16* __restrict__ A, const u16* __restrict__ B,
                                               const float* __restrict__ bias, void* __restrict__ Cv,
                                               const float* __restrict__ att_s,
                                               const float* __restrict__ att_d,
                                               float* __restrict__ a_srcO, float* __restrict__ a_dstO,
                                               int M, int N, int K) {
  __shared__ u16 sA[128 * 32];
  __shared__ u16 sB[128 * 32];
  int tid = threadIdx.x;
  int wv = tid >> 6;
  int lane = tid & 63;
  int quad = lane >> 4;
  int l16 = lane & 15;
  int m0 = blockIdx.x * 128;
  int n0g = blockIdx.y * 128;
  int rm = (wv >> 1) * 64;             // wave row base in tile
  int cn = (wv & 1) * 64;              // wave col base in tile

  f32x4 acc[4][4];
  #pragma unroll
  for (int mi = 0; mi < 4; ++mi)
    #pragma unroll
    for (int ni = 0; ni < 4; ++ni) acc[mi][ni] = f32x4{0.f, 0.f, 0.f, 0.f};

  for (int k0 = 0; k0 < K; k0 += 32) {
    // stage A,B tiles (128 rows x 32 cols bf16 = 8192 B each; 2 chunks of 1024 B per wave)
    #pragma unroll
    for (int q = 0; q < 2; ++q) {
      int off = (q * 4 + wv) * 1024 + lane * 16;   // byte offset in tile
      int row = off >> 6;                           // 64 B per row
      int kk = (off & 63) >> 1;                     // u16 col within row
      int rg = m0 + row; if (rg >= M) rg = M - 1;
      gl2lds16(A + (size_t)rg * K + k0 + kk, &sA[off >> 1]);
      gl2lds16(B + (size_t)(n0g + row) * K + k0 + kk, &sB[off >> 1]);
    }
    __syncthreads();
    bf16x8 af[4], bf[4];
    #pragma unroll
    for (int mi = 0; mi < 4; ++mi)
      af[mi] = *(const bf16x8*)&sA[(rm + mi * 16 + l16) * 32 + quad * 8];
    #pragma unroll
    for (int ni = 0; ni < 4; ++ni)
      bf[ni] = *(const bf16x8*)&sB[(cn + ni * 16 + l16) * 32 + quad * 8];
    #pragma unroll
    for (int mi = 0; mi < 4; ++mi)
      #pragma unroll
      for (int ni = 0; ni < 4; ++ni)
        acc[mi][ni] = __builtin_amdgcn_mfma_f32_16x16x32_bf16(af[mi], bf[ni], acc[mi][ni], 0, 0, 0);
    __syncthreads();
  }

  int h = n0g >> 7;                    // one head per 128-col block
  if (DOTS) {
    float av_s[4], av_d[4];
    #pragma unroll
    for (int ni = 0; ni < 4; ++ni) {
      int col = n0g + cn + ni * 16 + l16;
      av_s[ni] = att_s[col];
      av_d[ni] = att_d[col];
    }
    int H = N >> 7;
    #pragma unroll
    for (int mi = 0; mi < 4; ++mi) {
      #pragma unroll
      for (int r = 0; r < 4; ++r) {
        float sp = 0.f, dp = 0.f;
        #pragma unroll
        for (int ni = 0; ni < 4; ++ni) {
          sp += acc[mi][ni][r] * av_s[ni];
          dp += acc[mi][ni][r] * av_d[ni];
        }
        #pragma unroll
        for (int w = 1; w < 16; w <<= 1) {   // reduce over the 16 col-lanes
          sp += __shfl_xor(sp, w, 64);
          dp += __shfl_xor(dp, w, 64);
        }
        int orow = m0 + rm + mi * 16 + quad * 4 + r;
        if (l16 == 0 && orow < M) {
          atomicAdd(&a_srcO[(size_t)orow * H + h], sp);
          atomicAdd(&a_dstO[(size_t)orow * H + h], dp);
        }
      }
    }
  }
  #pragma unroll
  for (int ni = 0; ni < 4; ++ni) {
    int col = n0g + cn + ni * 16 + l16;
    float bv = BIAS ? bias[col] : 0.f;
    #pragma unroll
    for (int mi = 0; mi < 4; ++mi) {
      #pragma unroll
      for (int r = 0; r < 4; ++r) {
        int orow = m0 + rm + mi * 16 + quad * 4 + r;
        if (orow < M) {
          float v = acc[mi][ni][r] + bv;
          if (OUTF32) {
            ((float*)Cv)[(size_t)orow * N + col] = v;
          } else if (HM) {
            ((u16*)Cv)[(size_t)h * ((size_t)NNODES * 128) + (size_t)orow * 128 + (col & 127)] = f2bf(v);
          } else {
            ((u16*)Cv)[(size_t)orow * N + col] = f2bf(v);
          }
        }
      }
    }
  }
}

// ---------------- alpha layer1 (H=8): head-major out [8][NETOT] ----------------
// one wave per dst; lane = i*8+h: one wave does softmax for all 8 heads.
__global__ __launch_bounds__(256) void alpha1_k(const int* __restrict__ offs,
                                                const int* __restrict__ csr_src,
                                                const float* __restrict__ a_src,
                                                const float* __restrict__ a_dst,
                                                float* __restrict__ alpha) {
  int wv = threadIdx.x >> 6;
  int dst = blockIdx.x * 4 + wv;
  if (dst >= NNODES) return;
  int l = threadIdx.x & 63;
  int h = l & 7, i = l >> 3;
  int off = offs[dst];
  int deg = offs[dst + 1] - off;
  const int* srcs = csr_src + off;
  float ad = a_dst[dst * 8 + h];
  float m = -1e30f, ssum = 0.f;
  float* out = alpha + (size_t)h * NETOT + off;
  if (deg <= 64) {
    int sl = srcs[l < deg ? l : deg - 1];       // coalesced preload
    float ev[8];
    #pragma unroll
    for (int t = 0; t < 8; ++t) {
      int jj = i + t * 8;
      float e = -1e30f;
      if (jj < deg) {
        int s = __builtin_amdgcn_readlane(sl, jj);
        e = lrelu(a_src[s * 8 + h] + ad);       // 8 h-lanes share s: 32-B segment
      }
      ev[t] = e;
      float nm = fmaxf(m, e);
      ssum = ssum * __expf(m - nm) + ((jj < deg) ? __expf(e - nm) : 0.f);
      m = nm;
    }
    #pragma unroll
    for (int w = 8; w < 64; w <<= 1) {          // reduce over i (lane bits 3..5)
      float om = __shfl_xor(m, w, 64);
      float os = __shfl_xor(ssum, w, 64);
      float nm = fmaxf(m, om);
      ssum = ssum * __expf(m - nm) + os * __expf(om - nm);
      m = nm;
    }
    float inv = 1.f / (ssum + 1e-16f);
    #pragma unroll
    for (int t = 0; t < 8; ++t) {
      int jj = i + t * 8;
      if (jj < deg) out[jj] = __expf(ev[t] - m) * inv;
    }
  } else {
    for (int j = i; j < deg; j += 8) {
      int s = srcs[j];
      float e = lrelu(a_src[s * 8 + h] + ad);
      float nm = fmaxf(m, e);
      ssum = ssum * __expf(m - nm) + __expf(e - nm);
      m = nm;
    }
    #pragma unroll
    for (int w = 8; w < 64; w <<= 1) {
      float om = __shfl_xor(m, w, 64);
      float os = __shfl_xor(ssum, w, 64);
      float nm = fmaxf(m, om);
      ssum = ssum * __expf(m - nm) + os * __expf(om - nm);
      m = nm;
    }
    float inv = 1.f / (ssum + 1e-16f);
    for (int j = i; j < deg; j += 8) {
      int s = srcs[j];
      float e = lrelu(a_src[s * 8 + h] + ad);
      out[j] = __expf(e - m) * inv;
    }
  }
}

// ---------------- alpha layer2 (H=1): only dst in [NCONS, NNODES) ----------------
__global__ __launch_bounds__(256) void alpha2_k(const int* __restrict__ offs,
                                                const int* __restrict__ csr_src,
                                                const float* __restrict__ a_src,
                                                const float* __restrict__ a_dst,
                                                float* __restrict__ alpha) {
  int wv = threadIdx.x >> 6;
  int dst = NCONS + blockIdx.x * 4 + wv;
  if (dst >= NNODES) return;
  int l = threadIdx.x & 63;
  int off = offs[dst];
  int deg = offs[dst + 1] - off;
  float ad = a_dst[dst];
  if (deg <= 64) {
    float e = -1e30f;
    if (l < deg) e = lrelu(a_src[csr_src[off + l]] + ad);
    float m = e;
    #pragma unroll
    for (int w = 1; w < 64; w <<= 1) m = fmaxf(m, __shfl_xor(m, w, 64));
    float p = (l < deg) ? __expf(e - m) : 0.f;
    float ssum = p;
    #pragma unroll
    for (int w = 1; w < 64; w <<= 1) ssum += __shfl_xor(ssum, w, 64);
    float inv = 1.f / (ssum + 1e-16f);
    if (l < deg) alpha[off + l] = p * inv;
  } else {
    float m = -1e30f, ssum = 0.f;
    for (int j = l; j < deg; j += 64) {
      float e = lrelu(a_src[csr_src[off + j]] + ad);
      float nm = fmaxf(m, e);
      ssum = ssum * __expf(m - nm) + __expf(e - nm);
      m = nm;
    }
    #pragma unroll
    for (int w = 1; w < 64; w <<= 1) {
      float om = __shfl_xor(m, w, 64);
      float os = __shfl_xor(ssum, w, 64);
      float nm = fmaxf(m, om);
      ssum = ssum * __expf(m - nm) + os * __expf(om - nm);
      m = nm;
    }
    float inv = 1.f / (ssum + 1e-16f);
    for (int j = l; j < deg; j += 64) {
      float e = lrelu(a_src[csr_src[off + j]] + ad);
      alpha[off + j] = __expf(e - m) * inv;
    }
  }
}

// ---------------- SpMM layer1: head-sliced xp1h, head-major alpha, 8-deep exact gather -------
// wave per (dst, head); h = blockIdx.x & 7 -> XCD affinity on 5 MB head slice.
// srcs+alpha preloaded coalesced into lanes; readlane -> SGPR index -> scalar-path address.
// 8 independent gathers in flight; exact remainder loop (no masked slots).
// Lane owns channels 2l,2l+1.
__global__ __launch_bounds__(256) void spmm1(const int* __restrict__ offs,
                                             const int* __restrict__ csr_src,
                                             const float* __restrict__ alp,
                                             const u16* __restrict__ xp1h,
                                             const float* __restrict__ bias,
                                             u16* __restrict__ out) {
  int h = blockIdx.x & 7;
  int wvi = threadIdx.x >> 6;
  int dst = (blockIdx.x >> 3) * 4 + wvi;
  if (dst >= NNODES) return;
  int l = threadIdx.x & 63;
  int off = offs[dst];
  int deg = offs[dst + 1] - off;
  const int* srcs = csr_src + off;
  const float* alb = alp + (size_t)h * NETOT + off;
  const u16* base = xp1h + (size_t)h * ((size_t)NNODES * 128) + l * 2;
  float a0 = 0.f, a1 = 0.f;
  for (int b0 = 0; b0 < deg; b0 += 64) {
    int cnt = deg - b0; if (cnt > 64) cnt = 64;
    int sv = srcs[b0 + (l < cnt ? l : cnt - 1)];      // coalesced preload
    float av = (l < cnt) ? alb[b0 + l] : 0.f;         // coalesced preload
    int j = 0;
    for (; j + 8 <= cnt; j += 8) {
      ushort2 uu[8];
      float ww[8];
      #pragma unroll
      for (int t = 0; t < 8; ++t) {                   // 8 independent gathers in flight
        int s = __builtin_amdgcn_readlane(sv, j + t); // SGPR
        ww[t] = readlane_f(av, j + t);                // SGPR
        uu[t] = *(const ushort2*)(base + (size_t)s * 128);
      }
      #pragma unroll
      for (int t = 0; t < 8; ++t) {
        a0 += ww[t] * bf2f(uu[t].x);
        a1 += ww[t] * bf2f(uu[t].y);
      }
    }
    for (; j < cnt; ++j) {                            // exact tail, no masking
      int s = __builtin_amdgcn_readlane(sv, j);
      float w = readlane_f(av, j);
      ushort2 u = *(const ushort2*)(base + (size_t)s * 128);
      a0 += w * bf2f(u.x);
      a1 += w * bf2f(u.y);
    }
  }
  int cg = h * 128 + l * 2;
  ushort2 o;
  o.x = f2bf(fmaxf(a0 + bias[cg], 0.f));
  o.y = f2bf(fmaxf(a1 + bias[cg + 1], 0.f));
  *(ushort2*)(out + (size_t)dst * 1024 + cg) = o;
}

// ---------------- SpMM layer2 (H=1): only dst in [NCONS, NNODES) ----------------
__global__ __launch_bounds__(256) void spmm2(const int* __restrict__ offs,
                                             const int* __restrict__ csr_src,
                                             const float* __restrict__ alpha,
                                             const u16* __restrict__ xp2,
                                             const float* __restrict__ bias,
                                             u16* __restrict__ out) {
  int wvi = threadIdx.x >> 6;
  int dst = NCONS + blockIdx.x * 4 + wvi;
  if (dst >= NNODES) return;
  int l = threadIdx.x & 63;
  int off = offs[dst];
  int deg = offs[dst + 1] - off;
  const int* srcs = csr_src + off;
  const float* al = alpha + off;
  const u16* base = xp2 + l * 2;
  float a0 = 0.f, a1 = 0.f;
  for (int b0 = 0; b0 < deg; b0 += 64) {
    int cnt = deg - b0; if (cnt > 64) cnt = 64;
    int sv = srcs[b0 + (l < cnt ? l : cnt - 1)];
    float av = (l < cnt) ? al[b0 + l] : 0.f;
    int j = 0;
    for (; j + 8 <= cnt; j += 8) {
      ushort2 uu[8];
      float ww[8];
      #pragma unroll
      for (int t = 0; t < 8; ++t) {
        int s = __builtin_amdgcn_readlane(sv, j + t);
        ww[t] = readlane_f(av, j + t);
        uu[t] = *(const ushort2*)(base + (size_t)s * 128);
      }
      #pragma unroll
      for (int t = 0; t < 8; ++t) {
        a0 += ww[t] * bf2f(uu[t].x);
        a1 += ww[t] * bf2f(uu[t].y);
      }
    }
    for (; j < cnt; ++j) {
      int s = __builtin_amdgcn_readlane(sv, j);
      float w = readlane_f(av, j);
      ushort2 u = *(const ushort2*)(base + (size_t)s * 128);
      a0 += w * bf2f(u.x);
      a1 += w * bf2f(u.y);
    }
  }
  int cg = l * 2;
  ushort2 o;
  o.x = f2bf(fmaxf(a0 + bias[cg], 0.f));
  o.y = f2bf(fmaxf(a1 + bias[cg + 1], 0.f));
  *(ushort2*)(out + (size_t)dst * 128 + cg) = o;
}

// ---------------- launch ----------------
extern "C" void kernel_launch(void* const* d_in, const int* in_sizes, int n_in,
                              void* d_out, int out_size, void* d_ws, size_t ws_size,
                              hipStream_t stream) {
  const float* cons    = (const float*)d_in[0];
  const float* cols    = (const float*)d_in[1];
  const float* node_W  = (const float*)d_in[2];
  const float* node_b  = (const float*)d_in[3];
  const float* col_W   = (const float*)d_in[4];
  const float* col_b   = (const float*)d_in[5];
  const float* W1      = (const float*)d_in[6];
  const float* att_s1  = (const float*)d_in[7];
  const float* att_d1  = (const float*)d_in[8];
  const float* b1      = (const float*)d_in[9];
  const float* W2      = (const float*)d_in[10];
  const float* att_s2  = (const float*)d_in[11];
  const float* att_d2  = (const float*)d_in[12];
  const float* b2      = (const float*)d_in[13];
  const float* out_W   = (const float*)d_in[14];
  const float* out_b   = (const float*)d_in[15];
  const int* edges     = (const int*)d_in[16];

  char* p = (char*)d_ws;
  auto alloc = [&](size_t bytes) {
    char* r = p;
    p += (bytes + 255) & ~(size_t)255;
    return r;
  };
  u16* emb0    = (u16*)alloc((size_t)NNODES * 128 * 2);        // bf16
  u16* xp1h    = (u16*)alloc((size_t)8 * NNODES * 128 * 2);    // bf16, head-major slices
  u16* emb2    = (u16*)alloc((size_t)NNODES * 1024 * 2);       // bf16
  u16* xp2     = (u16*)alloc((size_t)NNODES * 128 * 2);        // bf16
  u16* emb3    = (u16*)alloc((size_t)NNODES * 128 * 2);        // bf16
  u16* Wbf     = (u16*)alloc((size_t)(W1N + W2N + OWN) * 2);   // W1|W2|out_W contiguous
  // ---- contiguous zero region: as1, ad1, as2, ad2, counts ----
  float* as1   = (float*)alloc((size_t)NNODES * 8 * 4);        // 640000 B (256-mult)
  float* ad1   = (float*)alloc((size_t)NNODES * 8 * 4);        // 640000 B
  float* as2   = (float*)alloc((size_t)NNODES * 4);            // pads to 80128 B
  float* ad2   = (float*)alloc((size_t)NNODES * 4);            // pads to 80128 B
  int* counts  = (int*)alloc((size_t)NNODES * 4);              // pads to 80128 B
  size_t zspan = (char*)(counts + NNODES) - (char*)as1;
  // ---- end zero region ----
  float* alp1  = (float*)alloc((size_t)8 * NETOT * 4);         // head-major [8][NETOT]
  float* alp2  = (float*)alloc((size_t)NETOT * 4);
  int* offs    = (int*)alloc((size_t)(NNODES + 1) * 4);
  int* cursor  = (int*)alloc((size_t)NNODES * 4);
  int* csrsrc  = (int*)alloc((size_t)NETOT * 4);
  int* lscan   = (int*)alloc((size_t)NSCANB * 256 * 4);
  int* bsum    = (int*)alloc((size_t)NSCANB * 4);
  int* bbase   = (int*)alloc((size_t)NSCANB * 4);

  u16* W1bf = Wbf;
  u16* W2bf = Wbf + W1N;
  u16* oWbf = Wbf + W1N + W2N;

  hipMemsetAsync(as1, 0, zspan, stream);

  // CSR build
  count_edges<<<(NETOT + 255) / 256, 256, 0, stream>>>(edges, counts);
  scan_a<<<NSCANB, 256, 0, stream>>>(counts, lscan, bsum);
  scan_b<<<1, 128, 0, stream>>>(bsum, bbase);
  scan_c<<<NSCANB, 256, 0, stream>>>(lscan, counts, bbase, offs, cursor);
  fill_edges<<<(NETOT + 255) / 256, 256, 0, stream>>>(edges, cursor, csrsrc);

  // layer 0 embed + weight conversions, fused
  prep<<<(EMB0N + W1N + W2N + OWN + 255) / 256, 256, 0, stream>>>(
      cons, cols, node_W, node_b, col_W, col_b, W1, W2, out_W, emb0, Wbf);

  // GAT layer 1: GEMM (fused dots, head-major out) -> alpha (head-major) -> SpMM
  gemm_bt<true, true, false, false><<<dim3((NNODES + 127) / 128, 1024 / 128), 256, 0, stream>>>(
      emb0, W1bf, nullptr, xp1h, att_s1, att_d1, as1, ad1, NNODES, 1024, 128);
  alpha1_k<<<(NNODES + 3) / 4, 256, 0, stream>>>(offs, csrsrc, as1, ad1, alp1);
  spmm1<<<8 * ((NNODES + 3) / 4), 256, 0, stream>>>(offs, csrsrc, alp1, xp1h, b1, emb2);

  // GAT layer 2: GEMM (fused dots) -> alpha -> SpMM (only dst >= NCONS needed)
  gemm_bt<true, false, false, false><<<dim3((NNODES + 127) / 128, 1), 256, 0, stream>>>(
      emb2, W2bf, nullptr, xp2, att_s2, att_d2, as2, ad2, NNODES, 128, 1024);
  alpha2_k<<<(NCOLSN + 3) / 4, 256, 0, stream>>>(offs, csrsrc, as2, ad2, alp2);
  spmm2<<<(NCOLSN + 3) / 4, 256, 0, stream>>>(offs, csrsrc, alp2, xp2, b2, emb3);

  // output projection: rows 10000..19999, f32 out with bias
  gemm_bt<false, false, true, true><<<dim3((NCOLSN + 127) / 128, 1), 256, 0, stream>>>(
      emb3 + (size_t)NCONS * 128, oWbf, out_b, d_out, nullptr, nullptr, nullptr, nullptr,
      NCOLSN, 128, 128);
}

// Round 12
// 311.167 us; speedup vs baseline: 1.0828x; 1.0259x over previous
//
#include <hip/hip_runtime.h>

// ---------------- problem constants ----------------
#define NCONS 10000
#define NCOLSN 10000
#define NNODES 20000         // NCONS + NCOLSN
#define NEDGE 200000
#define NETOT 220000         // NEDGE + NNODES self loops
#define NEG_SLOPE 0.2f
#define NSCANB 79            // ceil(NNODES/256)

typedef unsigned short u16;
typedef __attribute__((ext_vector_type(8))) short bf16x8;
typedef __attribute__((ext_vector_type(4))) float f32x4;

__device__ __forceinline__ float bf2f(u16 u) {
  return __uint_as_float(((unsigned int)u) << 16);
}
__device__ __forceinline__ u16 f2bf(float f) {
  unsigned int x = __float_as_uint(f);
  return (u16)((x + 0x7fffu + ((x >> 16) & 1u)) >> 16);
}
__device__ __forceinline__ float lrelu(float v) {
  return v >= 0.f ? v : NEG_SLOPE * v;
}
// async global->LDS, 16 B per lane; LDS dest must be wave-uniform base + lane*16
__device__ __forceinline__ void gl2lds16(const u16* g, u16* l) {
  __builtin_amdgcn_global_load_lds(
      (const __attribute__((address_space(1))) unsigned int*)g,
      (__attribute__((address_space(3))) unsigned int*)l, 16, 0, 0);
}
__device__ __forceinline__ float readlane_f(float v, int j) {
  return __uint_as_float(__builtin_amdgcn_readlane(__float_as_uint(v), j));
}

#define W1N (1024 * 128)
#define W2N (128 * 1024)
#define OWN (128 * 128)
#define EMB0N (NNODES * 128)

// ---------------- fused: layer-0 embed + weight f32->bf16 conversion ----------------
__global__ void prep(const float* __restrict__ cons, const float* __restrict__ cols,
                     const float* __restrict__ nW, const float* __restrict__ nb,
                     const float* __restrict__ cW, const float* __restrict__ cb,
                     const float* __restrict__ W1, const float* __restrict__ W2,
                     const float* __restrict__ oW, u16* __restrict__ emb,
                     u16* __restrict__ Wbf) {
  int idx = blockIdx.x * 256 + threadIdx.x;
  if (idx < EMB0N) {
    int row = idx >> 7, o = idx & 127;
    float acc;
    if (row < NCONS) {
      acc = nb[o];
      #pragma unroll
      for (int k = 0; k < 4; ++k)
        acc += cons[row * 4 + k] * (nW[o * 8 + k] + nW[o * 8 + 4 + k]);
    } else {
      int r = row - NCONS;
      acc = cb[o];
      #pragma unroll
      for (int k = 0; k < 8; ++k)
        acc += cols[r * 8 + k] * (cW[o * 16 + k] + cW[o * 16 + 8 + k]);
    }
    emb[idx] = f2bf(fmaxf(acc, 0.f));
  } else {
    int i = idx - EMB0N;
    if (i >= W1N + W2N + OWN) return;
    float v;
    if (i < W1N) v = W1[i];
    else if (i < W1N + W2N) v = W2[i - W1N];
    else v = oW[i - W1N - W2N];
    Wbf[i] = f2bf(v);
  }
}

// ---------------- CSR build ----------------
__global__ void count_edges(const int* __restrict__ edges, int* __restrict__ counts) {
  int i = blockIdx.x * 256 + threadIdx.x;
  if (i >= NETOT) return;
  int dst = (i < NEDGE) ? edges[NEDGE + i] : (i - NEDGE);
  atomicAdd(&counts[dst], 1);
}

__global__ void scan_a(const int* __restrict__ counts, int* __restrict__ lscan,
                       int* __restrict__ bsum) {
  __shared__ int sh[256];
  int t = threadIdx.x;
  int i = blockIdx.x * 256 + t;
  int v = (i < NNODES) ? counts[i] : 0;
  sh[t] = v;
  __syncthreads();
  for (int d = 1; d < 256; d <<= 1) {
    int add = (t >= d) ? sh[t - d] : 0;
    __syncthreads();
    sh[t] += add;
    __syncthreads();
  }
  lscan[i] = sh[t];
  if (t == 255) bsum[blockIdx.x] = sh[255];
}
__global__ void scan_b(const int* __restrict__ bsum, int* __restrict__ bbase) {
  __shared__ int sh[128];
  int t = threadIdx.x;
  int v = (t < NSCANB) ? bsum[t] : 0;
  sh[t] = v;
  __syncthreads();
  for (int d = 1; d < 128; d <<= 1) {
    int add = (t >= d) ? sh[t - d] : 0;
    __syncthreads();
    sh[t] += add;
    __syncthreads();
  }
  if (t < NSCANB) bbase[t] = sh[t] - v;
}
__global__ void scan_c(const int* __restrict__ lscan, const int* __restrict__ counts,
                       const int* __restrict__ bbase, int* __restrict__ offsets,
                       int* __restrict__ cursor) {
  int t = threadIdx.x;
  int i = blockIdx.x * 256 + t;
  if (i == 0) offsets[0] = 0;
  if (i < NNODES) {
    int incl = lscan[i] + bbase[blockIdx.x];
    offsets[i + 1] = incl;
    cursor[i] = incl - counts[i];
  }
}

__global__ void fill_edges(const int* __restrict__ edges, int* __restrict__ cursor,
                           int* __restrict__ csr_src) {
  int i = blockIdx.x * 256 + threadIdx.x;
  if (i >= NETOT) return;
  int src, dst;
  if (i < NEDGE) { src = edges[i]; dst = edges[NEDGE + i]; }
  else { src = dst = i - NEDGE; }
  int pos = atomicAdd(&cursor[dst], 1);
  csr_src[pos] = src;
}

// ---------------- LDS-staged GEMM (m97 structure): C[M,N] = A[M,K] @ B[N,K]^T ----------------
// BM x 128 block tile, BK=32, 256 thr = 4 waves (2x2 wave grid; wave = (BM/2) x 64,
// MI = BM/32 MFMA row-tiles of 16x16x32). BM=128 for big grids, BM=32 for small-N GEMMs
// (more blocks/CU -> inter-block overlap hides the 2-barrier K-loop drains).
// DOTS: fused attention-dot partials -> atomicAdd a_src/a_dst [M, N/128] (h = blockIdx.y)
// HM:   head-major store C[(col>>7)][row][col&127], slice stride NNODES*128
template <int BM, bool DOTS, bool HM, bool BIAS, bool OUTF32>
__global__ __launch_bounds__(256) void gemm_bt(const u16* __restrict__ A, const u16* __restrict__ B,
                                               const float* __restrict__ bias, void* __restrict__ Cv,
                                               const float* __restrict__ att_s,
                                               const float* __restrict__ att_d,
                                               float* __restrict__ a_srcO, float* __restrict__ a_dstO,
                                               int M, int N, int K) {
  constexpr int MI = BM / 32;          // MFMA row-tiles per wave (BM=128 -> 4, BM=32 -> 1)
  __shared__ u16 sA[BM * 32];
  __shared__ u16 sB[128 * 32];
  int tid = threadIdx.x;
  int wv = tid >> 6;
  int lane = tid & 63;
  int quad = lane >> 4;
  int l16 = lane & 15;
  int m0 = blockIdx.x * BM;
  int n0g = blockIdx.y * 128;
  int rm = (wv >> 1) * (16 * MI);      // wave row base in tile
  int cn = (wv & 1) * 64;              // wave col base in tile

  f32x4 acc[MI][4];
  #pragma unroll
  for (int mi = 0; mi < MI; ++mi)
    #pragma unroll
    for (int ni = 0; ni < 4; ++ni) acc[mi][ni] = f32x4{0.f, 0.f, 0.f, 0.f};

  for (int k0 = 0; k0 < K; k0 += 32) {
    // stage A (BM x 32) and B (128 x 32) tiles; 16 B per thread per pass, linear in tid
    for (int off = tid * 16; off < BM * 64; off += 4096) {
      int row = off >> 6;                           // 64 B per row
      int kk = (off & 63) >> 1;                     // u16 col within row
      int rg = m0 + row; if (rg >= M) rg = M - 1;
      gl2lds16(A + (size_t)rg * K + k0 + kk, &sA[off >> 1]);
    }
    for (int off = tid * 16; off < 128 * 64; off += 4096) {
      int row = off >> 6;
      int kk = (off & 63) >> 1;
      gl2lds16(B + (size_t)(n0g + row) * K + k0 + kk, &sB[off >> 1]);
    }
    __syncthreads();
    bf16x8 af[MI], bf[4];
    #pragma unroll
    for (int mi = 0; mi < MI; ++mi)
      af[mi] = *(const bf16x8*)&sA[(rm + mi * 16 + l16) * 32 + quad * 8];
    #pragma unroll
    for (int ni = 0; ni < 4; ++ni)
      bf[ni] = *(const bf16x8*)&sB[(cn + ni * 16 + l16) * 32 + quad * 8];
    #pragma unroll
    for (int mi = 0; mi < MI; ++mi)
      #pragma unroll
      for (int ni = 0; ni < 4; ++ni)
        acc[mi][ni] = __builtin_amdgcn_mfma_f32_16x16x32_bf16(af[mi], bf[ni], acc[mi][ni], 0, 0, 0);
    __syncthreads();
  }

  int h = n0g >> 7;                    // one head per 128-col block
  if (DOTS) {
    float av_s[4], av_d[4];
    #pragma unroll
    for (int ni = 0; ni < 4; ++ni) {
      int col = n0g + cn + ni * 16 + l16;
      av_s[ni] = att_s[col];
      av_d[ni] = att_d[col];
    }
    int H = N >> 7;
    #pragma unroll
    for (int mi = 0; mi < MI; ++mi) {
      #pragma unroll
      for (int r = 0; r < 4; ++r) {
        float sp = 0.f, dp = 0.f;
        #pragma unroll
        for (int ni = 0; ni < 4; ++ni) {
          sp += acc[mi][ni][r] * av_s[ni];
          dp += acc[mi][ni][r] * av_d[ni];
        }
        #pragma unroll
        for (int w = 1; w < 16; w <<= 1) {   // reduce over the 16 col-lanes
          sp += __shfl_xor(sp, w, 64);
          dp += __shfl_xor(dp, w, 64);
        }
        int orow = m0 + rm + mi * 16 + quad * 4 + r;
        if (l16 == 0 && orow < M) {
          atomicAdd(&a_srcO[(size_t)orow * H + h], sp);
          atomicAdd(&a_dstO[(size_t)orow * H + h], dp);
        }
      }
    }
  }
  #pragma unroll
  for (int ni = 0; ni < 4; ++ni) {
    int col = n0g + cn + ni * 16 + l16;
    float bv = BIAS ? bias[col] : 0.f;
    #pragma unroll
    for (int mi = 0; mi < MI; ++mi) {
      #pragma unroll
      for (int r = 0; r < 4; ++r) {
        int orow = m0 + rm + mi * 16 + quad * 4 + r;
        if (orow < M) {
          float v = acc[mi][ni][r] + bv;
          if (OUTF32) {
            ((float*)Cv)[(size_t)orow * N + col] = v;
          } else if (HM) {
            ((u16*)Cv)[(size_t)h * ((size_t)NNODES * 128) + (size_t)orow * 128 + (col & 127)] = f2bf(v);
          } else {
            ((u16*)Cv)[(size_t)orow * N + col] = f2bf(v);
          }
        }
      }
    }
  }
}

// ---------------- alpha layer1 (H=8): head-major out [8][NETOT] ----------------
// one wave per dst; lane = i*8+h: one wave does softmax for all 8 heads.
__global__ __launch_bounds__(256) void alpha1_k(const int* __restrict__ offs,
                                                const int* __restrict__ csr_src,
                                                const float* __restrict__ a_src,
                                                const float* __restrict__ a_dst,
                                                float* __restrict__ alpha) {
  int wv = threadIdx.x >> 6;
  int dst = blockIdx.x * 4 + wv;
  if (dst >= NNODES) return;
  int l = threadIdx.x & 63;
  int h = l & 7, i = l >> 3;
  int off = offs[dst];
  int deg = offs[dst + 1] - off;
  const int* srcs = csr_src + off;
  float ad = a_dst[dst * 8 + h];
  float m = -1e30f, ssum = 0.f;
  float* out = alpha + (size_t)h * NETOT + off;
  if (deg <= 64) {
    int sl = srcs[l < deg ? l : deg - 1];       // coalesced preload
    float ev[8];
    #pragma unroll
    for (int t = 0; t < 8; ++t) {
      int jj = i + t * 8;
      float e = -1e30f;
      if (jj < deg) {
        int s = __builtin_amdgcn_readlane(sl, jj);
        e = lrelu(a_src[s * 8 + h] + ad);       // 8 h-lanes share s: 32-B segment
      }
      ev[t] = e;
      float nm = fmaxf(m, e);
      ssum = ssum * __expf(m - nm) + ((jj < deg) ? __expf(e - nm) : 0.f);
      m = nm;
    }
    #pragma unroll
    for (int w = 8; w < 64; w <<= 1) {          // reduce over i (lane bits 3..5)
      float om = __shfl_xor(m, w, 64);
      float os = __shfl_xor(ssum, w, 64);
      float nm = fmaxf(m, om);
      ssum = ssum * __expf(m - nm) + os * __expf(om - nm);
      m = nm;
    }
    float inv = 1.f / (ssum + 1e-16f);
    #pragma unroll
    for (int t = 0; t < 8; ++t) {
      int jj = i + t * 8;
      if (jj < deg) out[jj] = __expf(ev[t] - m) * inv;
    }
  } else {
    for (int j = i; j < deg; j += 8) {
      int s = srcs[j];
      float e = lrelu(a_src[s * 8 + h] + ad);
      float nm = fmaxf(m, e);
      ssum = ssum * __expf(m - nm) + __expf(e - nm);
      m = nm;
    }
    #pragma unroll
    for (int w = 8; w < 64; w <<= 1) {
      float om = __shfl_xor(m, w, 64);
      float os = __shfl_xor(ssum, w, 64);
      float nm = fmaxf(m, om);
      ssum = ssum * __expf(m - nm) + os * __expf(om - nm);
      m = nm;
    }
    float inv = 1.f / (ssum + 1e-16f);
    for (int j = i; j < deg; j += 8) {
      int s = srcs[j];
      float e = lrelu(a_src[s * 8 + h] + ad);
      out[j] = __expf(e - m) * inv;
    }
  }
}

// ---------------- alpha layer2 (H=1): only dst in [NCONS, NNODES) ----------------
__global__ __launch_bounds__(256) void alpha2_k(const int* __restrict__ offs,
                                                const int* __restrict__ csr_src,
                                                const float* __restrict__ a_src,
                                                const float* __restrict__ a_dst,
                                                float* __restrict__ alpha) {
  int wv = threadIdx.x >> 6;
  int dst = NCONS + blockIdx.x * 4 + wv;
  if (dst >= NNODES) return;
  int l = threadIdx.x & 63;
  int off = offs[dst];
  int deg = offs[dst + 1] - off;
  float ad = a_dst[dst];
  if (deg <= 64) {
    float e = -1e30f;
    if (l < deg) e = lrelu(a_src[csr_src[off + l]] + ad);
    float m = e;
    #pragma unroll
    for (int w = 1; w < 64; w <<= 1) m = fmaxf(m, __shfl_xor(m, w, 64));
    float p = (l < deg) ? __expf(e - m) : 0.f;
    float ssum = p;
    #pragma unroll
    for (int w = 1; w < 64; w <<= 1) ssum += __shfl_xor(ssum, w, 64);
    float inv = 1.f / (ssum + 1e-16f);
    if (l < deg) alpha[off + l] = p * inv;
  } else {
    float m = -1e30f, ssum = 0.f;
    for (int j = l; j < deg; j += 64) {
      float e = lrelu(a_src[csr_src[off + j]] + ad);
      float nm = fmaxf(m, e);
      ssum = ssum * __expf(m - nm) + __expf(e - nm);
      m = nm;
    }
    #pragma unroll
    for (int w = 1; w < 64; w <<= 1) {
      float om = __shfl_xor(m, w, 64);
      float os = __shfl_xor(ssum, w, 64);
      float nm = fmaxf(m, om);
      ssum = ssum * __expf(m - nm) + os * __expf(om - nm);
      m = nm;
    }
    float inv = 1.f / (ssum + 1e-16f);
    for (int j = l; j < deg; j += 64) {
      float e = lrelu(a_src[csr_src[off + j]] + ad);
      alpha[off + j] = __expf(e - m) * inv;
    }
  }
}

// ---------------- SpMM layer1: head-sliced xp1h, head-major alpha, 8-deep exact gather -------
// wave per (dst, head); h = blockIdx.x & 7 -> XCD affinity on 5 MB head slice.
// srcs+alpha preloaded coalesced into lanes; readlane -> SGPR index -> scalar-path address.
// 8 independent gathers in flight; exact remainder loop (no masked slots).
// Lane owns channels 2l,2l+1.
__global__ __launch_bounds__(256) void spmm1(const int* __restrict__ offs,
                                             const int* __restrict__ csr_src,
                                             const float* __restrict__ alp,
                                             const u16* __restrict__ xp1h,
                                             const float* __restrict__ bias,
                                             u16* __restrict__ out) {
  int h = blockIdx.x & 7;
  int wvi = threadIdx.x >> 6;
  int dst = (blockIdx.x >> 3) * 4 + wvi;
  if (dst >= NNODES) return;
  int l = threadIdx.x & 63;
  int off = offs[dst];
  int deg = offs[dst + 1] - off;
  const int* srcs = csr_src + off;
  const float* alb = alp + (size_t)h * NETOT + off;
  const u16* base = xp1h + (size_t)h * ((size_t)NNODES * 128) + l * 2;
  float a0 = 0.f, a1 = 0.f;
  for (int b0 = 0; b0 < deg; b0 += 64) {
    int cnt = deg - b0; if (cnt > 64) cnt = 64;
    int sv = srcs[b0 + (l < cnt ? l : cnt - 1)];      // coalesced preload
    float av = (l < cnt) ? alb[b0 + l] : 0.f;         // coalesced preload
    int j = 0;
    for (; j + 8 <= cnt; j += 8) {
      ushort2 uu[8];
      float ww[8];
      #pragma unroll
      for (int t = 0; t < 8; ++t) {                   // 8 independent gathers in flight
        int s = __builtin_amdgcn_readlane(sv, j + t); // SGPR
        ww[t] = readlane_f(av, j + t);                // SGPR
        uu[t] = *(const ushort2*)(base + (size_t)s * 128);
      }
      #pragma unroll
      for (int t = 0; t < 8; ++t) {
        a0 += ww[t] * bf2f(uu[t].x);
        a1 += ww[t] * bf2f(uu[t].y);
      }
    }
    for (; j < cnt; ++j) {                            // exact tail, no masking
      int s = __builtin_amdgcn_readlane(sv, j);
      float w = readlane_f(av, j);
      ushort2 u = *(const ushort2*)(base + (size_t)s * 128);
      a0 += w * bf2f(u.x);
      a1 += w * bf2f(u.y);
    }
  }
  int cg = h * 128 + l * 2;
  ushort2 o;
  o.x = f2bf(fmaxf(a0 + bias[cg], 0.f));
  o.y = f2bf(fmaxf(a1 + bias[cg + 1], 0.f));
  *(ushort2*)(out + (size_t)dst * 1024 + cg) = o;
}

// ---------------- SpMM layer2 (H=1): only dst in [NCONS, NNODES) ----------------
__global__ __launch_bounds__(256) void spmm2(const int* __restrict__ offs,
                                             const int* __restrict__ csr_src,
                                             const float* __restrict__ alpha,
                                             const u16* __restrict__ xp2,
                                             const float* __restrict__ bias,
                                             u16* __restrict__ out) {
  int wvi = threadIdx.x >> 6;
  int dst = NCONS + blockIdx.x * 4 + wvi;
  if (dst >= NNODES) return;
  int l = threadIdx.x & 63;
  int off = offs[dst];
  int deg = offs[dst + 1] - off;
  const int* srcs = csr_src + off;
  const float* al = alpha + off;
  const u16* base = xp2 + l * 2;
  float a0 = 0.f, a1 = 0.f;
  for (int b0 = 0; b0 < deg; b0 += 64) {
    int cnt = deg - b0; if (cnt > 64) cnt = 64;
    int sv = srcs[b0 + (l < cnt ? l : cnt - 1)];
    float av = (l < cnt) ? al[b0 + l] : 0.f;
    int j = 0;
    for (; j + 8 <= cnt; j += 8) {
      ushort2 uu[8];
      float ww[8];
      #pragma unroll
      for (int t = 0; t < 8; ++t) {
        int s = __builtin_amdgcn_readlane(sv, j + t);
        ww[t] = readlane_f(av, j + t);
        uu[t] = *(const ushort2*)(base + (size_t)s * 128);
      }
      #pragma unroll
      for (int t = 0; t < 8; ++t) {
        a0 += ww[t] * bf2f(uu[t].x);
        a1 += ww[t] * bf2f(uu[t].y);
      }
    }
    for (; j < cnt; ++j) {
      int s = __builtin_amdgcn_readlane(sv, j);
      float w = readlane_f(av, j);
      ushort2 u = *(const ushort2*)(base + (size_t)s * 128);
      a0 += w * bf2f(u.x);
      a1 += w * bf2f(u.y);
    }
  }
  int cg = l * 2;
  ushort2 o;
  o.x = f2bf(fmaxf(a0 + bias[cg], 0.f));
  o.y = f2bf(fmaxf(a1 + bias[cg + 1], 0.f));
  *(ushort2*)(out + (size_t)dst * 128 + cg) = o;
}

// ---------------- launch ----------------
extern "C" void kernel_launch(void* const* d_in, const int* in_sizes, int n_in,
                              void* d_out, int out_size, void* d_ws, size_t ws_size,
                              hipStream_t stream) {
  const float* cons    = (const float*)d_in[0];
  const float* cols    = (const float*)d_in[1];
  const float* node_W  = (const float*)d_in[2];
  const float* node_b  = (const float*)d_in[3];
  const float* col_W   = (const float*)d_in[4];
  const float* col_b   = (const float*)d_in[5];
  const float* W1      = (const float*)d_in[6];
  const float* att_s1  = (const float*)d_in[7];
  const float* att_d1  = (const float*)d_in[8];
  const float* b1      = (const float*)d_in[9];
  const float* W2      = (const float*)d_in[10];
  const float* att_s2  = (const float*)d_in[11];
  const float* att_d2  = (const float*)d_in[12];
  const float* b2      = (const float*)d_in[13];
  const float* out_W   = (const float*)d_in[14];
  const float* out_b   = (const float*)d_in[15];
  const int* edges     = (const int*)d_in[16];

  char* p = (char*)d_ws;
  auto alloc = [&](size_t bytes) {
    char* r = p;
    p += (bytes + 255) & ~(size_t)255;
    return r;
  };
  u16* emb0    = (u16*)alloc((size_t)NNODES * 128 * 2);        // bf16
  u16* xp1h    = (u16*)alloc((size_t)8 * NNODES * 128 * 2);    // bf16, head-major slices
  u16* emb2    = (u16*)alloc((size_t)NNODES * 1024 * 2);       // bf16
  u16* xp2     = (u16*)alloc((size_t)NNODES * 128 * 2);        // bf16
  u16* emb3    = (u16*)alloc((size_t)NNODES * 128 * 2);        // bf16
  u16* Wbf     = (u16*)alloc((size_t)(W1N + W2N + OWN) * 2);   // W1|W2|out_W contiguous
  // ---- contiguous zero region: as1, ad1, as2, ad2, counts ----
  float* as1   = (float*)alloc((size_t)NNODES * 8 * 4);        // 640000 B (256-mult)
  float* ad1   = (float*)alloc((size_t)NNODES * 8 * 4);        // 640000 B
  float* as2   = (float*)alloc((size_t)NNODES * 4);            // pads to 80128 B
  float* ad2   = (float*)alloc((size_t)NNODES * 4);            // pads to 80128 B
  int* counts  = (int*)alloc((size_t)NNODES * 4);              // pads to 80128 B
  size_t zspan = (char*)(counts + NNODES) - (char*)as1;
  // ---- end zero region ----
  float* alp1  = (float*)alloc((size_t)8 * NETOT * 4);         // head-major [8][NETOT]
  float* alp2  = (float*)alloc((size_t)NETOT * 4);
  int* offs    = (int*)alloc((size_t)(NNODES + 1) * 4);
  int* cursor  = (int*)alloc((size_t)NNODES * 4);
  int* csrsrc  = (int*)alloc((size_t)NETOT * 4);
  int* lscan   = (int*)alloc((size_t)NSCANB * 256 * 4);
  int* bsum    = (int*)alloc((size_t)NSCANB * 4);
  int* bbase   = (int*)alloc((size_t)NSCANB * 4);

  u16* W1bf = Wbf;
  u16* W2bf = Wbf + W1N;
  u16* oWbf = Wbf + W1N + W2N;

  hipMemsetAsync(as1, 0, zspan, stream);

  // CSR build
  count_edges<<<(NETOT + 255) / 256, 256, 0, stream>>>(edges, counts);
  scan_a<<<NSCANB, 256, 0, stream>>>(counts, lscan, bsum);
  scan_b<<<1, 128, 0, stream>>>(bsum, bbase);
  scan_c<<<NSCANB, 256, 0, stream>>>(lscan, counts, bbase, offs, cursor);
  fill_edges<<<(NETOT + 255) / 256, 256, 0, stream>>>(edges, cursor, csrsrc);

  // layer 0 embed + weight conversions, fused
  prep<<<(EMB0N + W1N + W2N + OWN + 255) / 256, 256, 0, stream>>>(
      cons, cols, node_W, node_b, col_W, col_b, W1, W2, out_W, emb0, Wbf);

  // GAT layer 1: GEMM (fused dots, head-major out) -> alpha (head-major) -> SpMM
  gemm_bt<128, true, true, false, false><<<dim3((NNODES + 127) / 128, 1024 / 128), 256, 0, stream>>>(
      emb0, W1bf, nullptr, xp1h, att_s1, att_d1, as1, ad1, NNODES, 1024, 128);
  alpha1_k<<<(NNODES + 3) / 4, 256, 0, stream>>>(offs, csrsrc, as1, ad1, alp1);
  spmm1<<<8 * ((NNODES + 3) / 4), 256, 0, stream>>>(offs, csrsrc, alp1, xp1h, b1, emb2);

  // GAT layer 2: GEMM (fused dots, BM=32 -> 625 blocks) -> alpha -> SpMM (dst >= NCONS only)
  gemm_bt<32, true, false, false, false><<<dim3((NNODES + 31) / 32, 1), 256, 0, stream>>>(
      emb2, W2bf, nullptr, xp2, att_s2, att_d2, as2, ad2, NNODES, 128, 1024);
  alpha2_k<<<(NCOLSN + 3) / 4, 256, 0, stream>>>(offs, csrsrc, as2, ad2, alp2);
  spmm2<<<(NCOLSN + 3) / 4, 256, 0, stream>>>(offs, csrsrc, alp2, xp2, b2, emb3);

  // output projection: rows 10000..19999, f32 out with bias (BM=32 -> 313 blocks)
  gemm_bt<32, false, false, true, true><<<dim3((NCOLSN + 31) / 32, 1), 256, 0, stream>>>(
      emb3 + (size_t)NCONS * 128, oWbf, out_b, d_out, nullptr, nullptr, nullptr, nullptr,
      NCOLSN, 128, 128);
}

// Round 13
// 302.974 us; speedup vs baseline: 1.1121x; 1.0270x over previous
//
#include <hip/hip_runtime.h>

// ---------------- problem constants ----------------
#define NCONS 10000
#define NCOLSN 10000
#define NNODES 20000         // NCONS + NCOLSN
#define NEDGE 200000
#define NETOT 220000         // NEDGE + NNODES self loops
#define NEG_SLOPE 0.2f
#define NSCANB 79            // ceil(NNODES/256)

typedef unsigned short u16;
typedef __attribute__((ext_vector_type(8))) short bf16x8;
typedef __attribute__((ext_vector_type(4))) float f32x4;

__device__ __forceinline__ float bf2f(u16 u) {
  return __uint_as_float(((unsigned int)u) << 16);
}
__device__ __forceinline__ u16 f2bf(float f) {
  unsigned int x = __float_as_uint(f);
  return (u16)((x + 0x7fffu + ((x >> 16) & 1u)) >> 16);
}
__device__ __forceinline__ float lrelu(float v) {
  return v >= 0.f ? v : NEG_SLOPE * v;
}
// async global->LDS, 16 B per lane; LDS dest must be wave-uniform base + lane*16
__device__ __forceinline__ void gl2lds16(const u16* g, u16* l) {
  __builtin_amdgcn_global_load_lds(
      (const __attribute__((address_space(1))) unsigned int*)g,
      (__attribute__((address_space(3))) unsigned int*)l, 16, 0, 0);
}
__device__ __forceinline__ float readlane_f(float v, int j) {
  return __uint_as_float(__builtin_amdgcn_readlane(__float_as_uint(v), j));
}

#define W1N (1024 * 128)
#define W2N (128 * 1024)
#define OWN (128 * 128)
#define EMB0N (NNODES * 128)

// ---------------- fused: layer-0 embed + weight cvt + edge counting ----------------
__global__ void prep(const float* __restrict__ cons, const float* __restrict__ cols,
                     const float* __restrict__ nW, const float* __restrict__ nb,
                     const float* __restrict__ cW, const float* __restrict__ cb,
                     const float* __restrict__ W1, const float* __restrict__ W2,
                     const float* __restrict__ oW, u16* __restrict__ emb,
                     u16* __restrict__ Wbf, const int* __restrict__ edges,
                     int* __restrict__ counts) {
  int idx = blockIdx.x * 256 + threadIdx.x;
  if (idx < NETOT) {
    int dst = (idx < NEDGE) ? edges[NEDGE + idx] : (idx - NEDGE);
    atomicAdd(&counts[dst], 1);
  }
  if (idx < EMB0N) {
    int row = idx >> 7, o = idx & 127;
    float acc;
    if (row < NCONS) {
      acc = nb[o];
      #pragma unroll
      for (int k = 0; k < 4; ++k)
        acc += cons[row * 4 + k] * (nW[o * 8 + k] + nW[o * 8 + 4 + k]);
    } else {
      int r = row - NCONS;
      acc = cb[o];
      #pragma unroll
      for (int k = 0; k < 8; ++k)
        acc += cols[r * 8 + k] * (cW[o * 16 + k] + cW[o * 16 + 8 + k]);
    }
    emb[idx] = f2bf(fmaxf(acc, 0.f));
  } else {
    int i = idx - EMB0N;
    if (i >= W1N + W2N + OWN) return;
    float v;
    if (i < W1N) v = W1[i];
    else if (i < W1N + W2N) v = W2[i - W1N];
    else v = oW[i - W1N - W2N];
    Wbf[i] = f2bf(v);
  }
}

// ---------------- CSR build ----------------
__global__ void scan_a(const int* __restrict__ counts, int* __restrict__ lscan,
                       int* __restrict__ bsum) {
  __shared__ int sh[256];
  int t = threadIdx.x;
  int i = blockIdx.x * 256 + t;
  int v = (i < NNODES) ? counts[i] : 0;
  sh[t] = v;
  __syncthreads();
  for (int d = 1; d < 256; d <<= 1) {
    int add = (t >= d) ? sh[t - d] : 0;
    __syncthreads();
    sh[t] += add;
    __syncthreads();
  }
  lscan[i] = sh[t];
  if (t == 255) bsum[blockIdx.x] = sh[255];
}
// combine: each block redundantly scans the 79 block sums in LDS, then emits offsets+cursor
__global__ void scan_c2(const int* __restrict__ lscan, const int* __restrict__ counts,
                        const int* __restrict__ bsum, int* __restrict__ offsets,
                        int* __restrict__ cursor) {
  __shared__ int sh[128];
  int t = threadIdx.x;
  if (t < 128) sh[t] = (t < NSCANB) ? bsum[t] : 0;
  __syncthreads();
  for (int d = 1; d < 128; d <<= 1) {
    int add = (t >= d && t < 128) ? sh[t - d] : 0;
    __syncthreads();
    if (t < 128) sh[t] += add;
    __syncthreads();
  }
  int bbase = (blockIdx.x > 0) ? sh[blockIdx.x - 1] : 0;   // exclusive base
  int i = blockIdx.x * 256 + t;
  if (i == 0) offsets[0] = 0;
  if (i < NNODES) {
    int incl = lscan[i] + bbase;
    offsets[i + 1] = incl;
    cursor[i] = incl - counts[i];
  }
}

__global__ void fill_edges(const int* __restrict__ edges, int* __restrict__ cursor,
                           int* __restrict__ csr_src) {
  int i = blockIdx.x * 256 + threadIdx.x;
  if (i >= NETOT) return;
  int src, dst;
  if (i < NEDGE) { src = edges[i]; dst = edges[NEDGE + i]; }
  else { src = dst = i - NEDGE; }
  int pos = atomicAdd(&cursor[dst], 1);
  csr_src[pos] = src;
}

// ---------------- LDS-staged GEMM (m97 structure): C[M,N] = A[M,K] @ B[N,K]^T ----------------
// BM x 128 block tile, BK=32, 256 thr = 4 waves (2x2 wave grid; MI = BM/32 row-tiles).
// DOTS: fused attention-dot partials -> atomicAdd a_src/a_dst [M, N/128] (h = blockIdx.y)
// HM:   head-major store C[(col>>7)][row][col&127], slice stride NNODES*128
template <int BM, bool DOTS, bool HM, bool BIAS, bool OUTF32>
__global__ __launch_bounds__(256) void gemm_bt(const u16* __restrict__ A, const u16* __restrict__ B,
                                               const float* __restrict__ bias, void* __restrict__ Cv,
                                               const float* __restrict__ att_s,
                                               const float* __restrict__ att_d,
                                               float* __restrict__ a_srcO, float* __restrict__ a_dstO,
                                               int M, int N, int K) {
  constexpr int MI = BM / 32;
  __shared__ u16 sA[BM * 32];
  __shared__ u16 sB[128 * 32];
  int tid = threadIdx.x;
  int wv = tid >> 6;
  int lane = tid & 63;
  int quad = lane >> 4;
  int l16 = lane & 15;
  int m0 = blockIdx.x * BM;
  int n0g = blockIdx.y * 128;
  int rm = (wv >> 1) * (16 * MI);
  int cn = (wv & 1) * 64;

  f32x4 acc[MI][4];
  #pragma unroll
  for (int mi = 0; mi < MI; ++mi)
    #pragma unroll
    for (int ni = 0; ni < 4; ++ni) acc[mi][ni] = f32x4{0.f, 0.f, 0.f, 0.f};

  for (int k0 = 0; k0 < K; k0 += 32) {
    for (int off = tid * 16; off < BM * 64; off += 4096) {
      int row = off >> 6;
      int kk = (off & 63) >> 1;
      int rg = m0 + row; if (rg >= M) rg = M - 1;
      gl2lds16(A + (size_t)rg * K + k0 + kk, &sA[off >> 1]);
    }
    for (int off = tid * 16; off < 128 * 64; off += 4096) {
      int row = off >> 6;
      int kk = (off & 63) >> 1;
      gl2lds16(B + (size_t)(n0g + row) * K + k0 + kk, &sB[off >> 1]);
    }
    __syncthreads();
    bf16x8 af[MI], bf[4];
    #pragma unroll
    for (int mi = 0; mi < MI; ++mi)
      af[mi] = *(const bf16x8*)&sA[(rm + mi * 16 + l16) * 32 + quad * 8];
    #pragma unroll
    for (int ni = 0; ni < 4; ++ni)
      bf[ni] = *(const bf16x8*)&sB[(cn + ni * 16 + l16) * 32 + quad * 8];
    #pragma unroll
    for (int mi = 0; mi < MI; ++mi)
      #pragma unroll
      for (int ni = 0; ni < 4; ++ni)
        acc[mi][ni] = __builtin_amdgcn_mfma_f32_16x16x32_bf16(af[mi], bf[ni], acc[mi][ni], 0, 0, 0);
    __syncthreads();
  }

  int h = n0g >> 7;
  if (DOTS) {
    float av_s[4], av_d[4];
    #pragma unroll
    for (int ni = 0; ni < 4; ++ni) {
      int col = n0g + cn + ni * 16 + l16;
      av_s[ni] = att_s[col];
      av_d[ni] = att_d[col];
    }
    int H = N >> 7;
    #pragma unroll
    for (int mi = 0; mi < MI; ++mi) {
      #pragma unroll
      for (int r = 0; r < 4; ++r) {
        float sp = 0.f, dp = 0.f;
        #pragma unroll
        for (int ni = 0; ni < 4; ++ni) {
          sp += acc[mi][ni][r] * av_s[ni];
          dp += acc[mi][ni][r] * av_d[ni];
        }
        #pragma unroll
        for (int w = 1; w < 16; w <<= 1) {
          sp += __shfl_xor(sp, w, 64);
          dp += __shfl_xor(dp, w, 64);
        }
        int orow = m0 + rm + mi * 16 + quad * 4 + r;
        if (l16 == 0 && orow < M) {
          atomicAdd(&a_srcO[(size_t)orow * H + h], sp);
          atomicAdd(&a_dstO[(size_t)orow * H + h], dp);
        }
      }
    }
  }
  #pragma unroll
  for (int ni = 0; ni < 4; ++ni) {
    int col = n0g + cn + ni * 16 + l16;
    float bv = BIAS ? bias[col] : 0.f;
    #pragma unroll
    for (int mi = 0; mi < MI; ++mi) {
      #pragma unroll
      for (int r = 0; r < 4; ++r) {
        int orow = m0 + rm + mi * 16 + quad * 4 + r;
        if (orow < M) {
          float v = acc[mi][ni][r] + bv;
          if (OUTF32) {
            ((float*)Cv)[(size_t)orow * N + col] = v;
          } else if (HM) {
            ((u16*)Cv)[(size_t)h * ((size_t)NNODES * 128) + (size_t)orow * 128 + (col & 127)] = f2bf(v);
          } else {
            ((u16*)Cv)[(size_t)orow * N + col] = f2bf(v);
          }
        }
      }
    }
  }
}

// ---------------- alpha layer1 (H=8): head-major out [8][NETOT] ----------------
// one wave per dst; lane = i*8+h. Gathers hoisted ahead of the softmax chain (8 in flight).
__global__ __launch_bounds__(256) void alpha1_k(const int* __restrict__ offs,
                                                const int* __restrict__ csr_src,
                                                const float* __restrict__ a_src,
                                                const float* __restrict__ a_dst,
                                                float* __restrict__ alpha) {
  int wv = threadIdx.x >> 6;
  int dst = blockIdx.x * 4 + wv;
  if (dst >= NNODES) return;
  int l = threadIdx.x & 63;
  int h = l & 7, i = l >> 3;
  int off = offs[dst];
  int deg = offs[dst + 1] - off;
  const int* srcs = csr_src + off;
  float ad = a_dst[dst * 8 + h];
  float m = -1e30f, ssum = 0.f;
  float* out = alpha + (size_t)h * NETOT + off;
  if (deg <= 64) {
    int sl = srcs[l < deg ? l : deg - 1];       // coalesced preload
    float g[8];
    #pragma unroll
    for (int t = 0; t < 8; ++t) {               // 8 independent gathers in flight
      int jj = i + t * 8;
      int s = __builtin_amdgcn_readlane(sl, jj < deg ? jj : 0);
      g[t] = a_src[s * 8 + h];                  // 8 h-lanes share s: 32-B segment
    }
    float ev[8];
    #pragma unroll
    for (int t = 0; t < 8; ++t) {
      int jj = i + t * 8;
      float e = (jj < deg) ? lrelu(g[t] + ad) : -1e30f;
      ev[t] = e;
      float nm = fmaxf(m, e);
      ssum = ssum * __expf(m - nm) + ((jj < deg) ? __expf(e - nm) : 0.f);
      m = nm;
    }
    #pragma unroll
    for (int w = 8; w < 64; w <<= 1) {          // reduce over i (lane bits 3..5)
      float om = __shfl_xor(m, w, 64);
      float os = __shfl_xor(ssum, w, 64);
      float nm = fmaxf(m, om);
      ssum = ssum * __expf(m - nm) + os * __expf(om - nm);
      m = nm;
    }
    float inv = 1.f / (ssum + 1e-16f);
    #pragma unroll
    for (int t = 0; t < 8; ++t) {
      int jj = i + t * 8;
      if (jj < deg) out[jj] = __expf(ev[t] - m) * inv;
    }
  } else {
    for (int j = i; j < deg; j += 8) {
      int s = srcs[j];
      float e = lrelu(a_src[s * 8 + h] + ad);
      float nm = fmaxf(m, e);
      ssum = ssum * __expf(m - nm) + __expf(e - nm);
      m = nm;
    }
    #pragma unroll
    for (int w = 8; w < 64; w <<= 1) {
      float om = __shfl_xor(m, w, 64);
      float os = __shfl_xor(ssum, w, 64);
      float nm = fmaxf(m, om);
      ssum = ssum * __expf(m - nm) + os * __expf(om - nm);
      m = nm;
    }
    float inv = 1.f / (ssum + 1e-16f);
    for (int j = i; j < deg; j += 8) {
      int s = srcs[j];
      float e = lrelu(a_src[s * 8 + h] + ad);
      out[j] = __expf(e - m) * inv;
    }
  }
}

// ---------------- SpMM layer1: head-sliced xp1h, head-major alpha, 8-deep exact gather -------
// wave per (dst, head); h = blockIdx.x & 7 -> XCD affinity on 5 MB head slice.
// srcs+alpha preloaded coalesced; readlane -> SGPR index -> scalar-path address.
// 8 independent gathers in flight; exact remainder loop. Lane owns channels 2l,2l+1.
__global__ __launch_bounds__(256) void spmm1(const int* __restrict__ offs,
                                             const int* __restrict__ csr_src,
                                             const float* __restrict__ alp,
                                             const u16* __restrict__ xp1h,
                                             const float* __restrict__ bias,
                                             u16* __restrict__ out) {
  int h = blockIdx.x & 7;
  int wvi = threadIdx.x >> 6;
  int dst = (blockIdx.x >> 3) * 4 + wvi;
  if (dst >= NNODES) return;
  int l = threadIdx.x & 63;
  int off = offs[dst];
  int deg = offs[dst + 1] - off;
  const int* srcs = csr_src + off;
  const float* alb = alp + (size_t)h * NETOT + off;
  const u16* base = xp1h + (size_t)h * ((size_t)NNODES * 128) + l * 2;
  float a0 = 0.f, a1 = 0.f;
  for (int b0 = 0; b0 < deg; b0 += 64) {
    int cnt = deg - b0; if (cnt > 64) cnt = 64;
    int sv = srcs[b0 + (l < cnt ? l : cnt - 1)];
    float av = (l < cnt) ? alb[b0 + l] : 0.f;
    int j = 0;
    for (; j + 8 <= cnt; j += 8) {
      ushort2 uu[8];
      float ww[8];
      #pragma unroll
      for (int t = 0; t < 8; ++t) {
        int s = __builtin_amdgcn_readlane(sv, j + t);
        ww[t] = readlane_f(av, j + t);
        uu[t] = *(const ushort2*)(base + (size_t)s * 128);
      }
      #pragma unroll
      for (int t = 0; t < 8; ++t) {
        a0 += ww[t] * bf2f(uu[t].x);
        a1 += ww[t] * bf2f(uu[t].y);
      }
    }
    for (; j < cnt; ++j) {
      int s = __builtin_amdgcn_readlane(sv, j);
      float w = readlane_f(av, j);
      ushort2 u = *(const ushort2*)(base + (size_t)s * 128);
      a0 += w * bf2f(u.x);
      a1 += w * bf2f(u.y);
    }
  }
  int cg = h * 128 + l * 2;
  ushort2 o;
  o.x = f2bf(fmaxf(a0 + bias[cg], 0.f));
  o.y = f2bf(fmaxf(a1 + bias[cg + 1], 0.f));
  *(ushort2*)(out + (size_t)dst * 1024 + cg) = o;
}

// ---------------- fused softmax + SpMM layer2 (H=1), dst in [NCONS, NNODES) ----------------
// wave per dst; lane-parallel e + wave softmax (online across chunks), pex kept in lanes,
// gather with 8-deep exact batches + tail. Lane owns channels 2l,2l+1.
__global__ __launch_bounds__(256) void fsp2(const int* __restrict__ offs,
                                            const int* __restrict__ csr_src,
                                            const float* __restrict__ a_src,
                                            const float* __restrict__ a_dst,
                                            const u16* __restrict__ xp2,
                                            const float* __restrict__ bias,
                                            u16* __restrict__ out) {
  int wvi = threadIdx.x >> 6;
  int dst = NCONS + blockIdx.x * 4 + wvi;
  if (dst >= NNODES) return;
  int l = threadIdx.x & 63;
  int off = offs[dst];
  int deg = offs[dst + 1] - off;
  const int* srcs = csr_src + off;
  float ad = a_dst[dst];
  const u16* base = xp2 + l * 2;
  float m = -1e30f, ssum = 0.f, a0 = 0.f, a1 = 0.f;
  for (int b0 = 0; b0 < deg; b0 += 64) {
    int cnt = deg - b0; if (cnt > 64) cnt = 64;
    int sv = srcs[b0 + (l < cnt ? l : cnt - 1)];
    float e = (l < cnt) ? lrelu(a_src[sv] + ad) : -1e30f;
    float mc = e;
    #pragma unroll
    for (int w = 1; w < 64; w <<= 1) mc = fmaxf(mc, __shfl_xor(mc, w, 64));
    float pex = __expf(e - mc);                 // invalid lanes -> 0
    float sc = pex;
    #pragma unroll
    for (int w = 1; w < 64; w <<= 1) sc += __shfl_xor(sc, w, 64);
    float c0 = 0.f, c1 = 0.f;
    int j = 0;
    for (; j + 8 <= cnt; j += 8) {
      ushort2 uu[8];
      float ww[8];
      #pragma unroll
      for (int t = 0; t < 8; ++t) {
        int s = __builtin_amdgcn_readlane(sv, j + t);
        ww[t] = readlane_f(pex, j + t);
        uu[t] = *(const ushort2*)(base + (size_t)s * 128);
      }
      #pragma unroll
      for (int t = 0; t < 8; ++t) {
        c0 += ww[t] * bf2f(uu[t].x);
        c1 += ww[t] * bf2f(uu[t].y);
      }
    }
    for (; j < cnt; ++j) {
      int s = __builtin_amdgcn_readlane(sv, j);
      float w = readlane_f(pex, j);
      ushort2 u = *(const ushort2*)(base + (size_t)s * 128);
      c0 += w * bf2f(u.x);
      c1 += w * bf2f(u.y);
    }
    float nm = fmaxf(m, mc);
    float fo = __expf(m - nm), fn = __expf(mc - nm);
    a0 = a0 * fo + c0 * fn;
    a1 = a1 * fo + c1 * fn;
    ssum = ssum * fo + sc * fn;
    m = nm;
  }
  float inv = 1.f / (ssum + 1e-16f);
  int cg = l * 2;
  ushort2 o;
  o.x = f2bf(fmaxf(a0 * inv + bias[cg], 0.f));
  o.y = f2bf(fmaxf(a1 * inv + bias[cg + 1], 0.f));
  *(ushort2*)(out + (size_t)dst * 128 + cg) = o;
}

// ---------------- launch ----------------
extern "C" void kernel_launch(void* const* d_in, const int* in_sizes, int n_in,
                              void* d_out, int out_size, void* d_ws, size_t ws_size,
                              hipStream_t stream) {
  const float* cons    = (const float*)d_in[0];
  const float* cols    = (const float*)d_in[1];
  const float* node_W  = (const float*)d_in[2];
  const float* node_b  = (const float*)d_in[3];
  const float* col_W   = (const float*)d_in[4];
  const float* col_b   = (const float*)d_in[5];
  const float* W1      = (const float*)d_in[6];
  const float* att_s1  = (const float*)d_in[7];
  const float* att_d1  = (const float*)d_in[8];
  const float* b1      = (const float*)d_in[9];
  const float* W2      = (const float*)d_in[10];
  const float* att_s2  = (const float*)d_in[11];
  const float* att_d2  = (const float*)d_in[12];
  const float* b2      = (const float*)d_in[13];
  const float* out_W   = (const float*)d_in[14];
  const float* out_b   = (const float*)d_in[15];
  const int* edges     = (const int*)d_in[16];

  char* p = (char*)d_ws;
  auto alloc = [&](size_t bytes) {
    char* r = p;
    p += (bytes + 255) & ~(size_t)255;
    return r;
  };
  u16* emb0    = (u16*)alloc((size_t)NNODES * 128 * 2);        // bf16
  u16* xp1h    = (u16*)alloc((size_t)8 * NNODES * 128 * 2);    // bf16, head-major slices
  u16* emb2    = (u16*)alloc((size_t)NNODES * 1024 * 2);       // bf16
  u16* xp2     = (u16*)alloc((size_t)NNODES * 128 * 2);        // bf16
  u16* emb3    = (u16*)alloc((size_t)NNODES * 128 * 2);        // bf16
  u16* Wbf     = (u16*)alloc((size_t)(W1N + W2N + OWN) * 2);   // W1|W2|out_W contiguous
  // ---- contiguous zero region: as1, ad1, as2, ad2, counts ----
  float* as1   = (float*)alloc((size_t)NNODES * 8 * 4);        // 640000 B (256-mult)
  float* ad1   = (float*)alloc((size_t)NNODES * 8 * 4);        // 640000 B
  float* as2   = (float*)alloc((size_t)NNODES * 4);            // pads to 80128 B
  float* ad2   = (float*)alloc((size_t)NNODES * 4);            // pads to 80128 B
  int* counts  = (int*)alloc((size_t)NNODES * 4);              // pads to 80128 B
  size_t zspan = (char*)(counts + NNODES) - (char*)as1;
  // ---- end zero region ----
  float* alp1  = (float*)alloc((size_t)8 * NETOT * 4);         // head-major [8][NETOT]
  int* offs    = (int*)alloc((size_t)(NNODES + 1) * 4);
  int* cursor  = (int*)alloc((size_t)NNODES * 4);
  int* csrsrc  = (int*)alloc((size_t)NETOT * 4);
  int* lscan   = (int*)alloc((size_t)NSCANB * 256 * 4);
  int* bsum    = (int*)alloc((size_t)NSCANB * 4);

  u16* W1bf = Wbf;
  u16* W2bf = Wbf + W1N;
  u16* oWbf = Wbf + W1N + W2N;

  hipMemsetAsync(as1, 0, zspan, stream);

  // layer-0 embed + weight cvt + edge counting (fused)
  prep<<<(EMB0N + W1N + W2N + OWN + 255) / 256, 256, 0, stream>>>(
      cons, cols, node_W, node_b, col_W, col_b, W1, W2, out_W, emb0, Wbf, edges, counts);

  // CSR build (scan_b folded into scan_c2)
  scan_a<<<NSCANB, 256, 0, stream>>>(counts, lscan, bsum);
  scan_c2<<<NSCANB, 256, 0, stream>>>(lscan, counts, bsum, offs, cursor);
  fill_edges<<<(NETOT + 255) / 256, 256, 0, stream>>>(edges, cursor, csrsrc);

  // GAT layer 1: GEMM (fused dots, head-major out) -> alpha (head-major) -> SpMM
  gemm_bt<128, true, true, false, false><<<dim3((NNODES + 127) / 128, 1024 / 128), 256, 0, stream>>>(
      emb0, W1bf, nullptr, xp1h, att_s1, att_d1, as1, ad1, NNODES, 1024, 128);
  alpha1_k<<<(NNODES + 3) / 4, 256, 0, stream>>>(offs, csrsrc, as1, ad1, alp1);
  spmm1<<<8 * ((NNODES + 3) / 4), 256, 0, stream>>>(offs, csrsrc, alp1, xp1h, b1, emb2);

  // GAT layer 2: GEMM (fused dots, BM=32) -> fused softmax+SpMM (dst >= NCONS only)
  gemm_bt<32, true, false, false, false><<<dim3((NNODES + 31) / 32, 1), 256, 0, stream>>>(
      emb2, W2bf, nullptr, xp2, att_s2, att_d2, as2, ad2, NNODES, 128, 1024);
  fsp2<<<(NCOLSN + 3) / 4, 256, 0, stream>>>(offs, csrsrc, as2, ad2, xp2, b2, emb3);

  // output projection: rows 10000..19999, f32 out with bias (BM=32)
  gemm_bt<32, false, false, true, true><<<dim3((NCOLSN + 31) / 32, 1), 256, 0, stream>>>(
      emb3 + (size_t)NCONS * 128, oWbf, out_b, d_out, nullptr, nullptr, nullptr, nullptr,
      NCOLSN, 128, 128);
}

// Round 14
// 261.925 us; speedup vs baseline: 1.2864x; 1.1567x over previous
//
#include <hip/hip_runtime.h>

// ---------------- problem constants ----------------
#define NCONS 10000
#define NCOLSN 10000
#define NNODES 20000         // NCONS + NCOLSN
#define NEDGE 200000
#define NETOT 220000         // NEDGE + NNODES self loops
#define NEG_SLOPE 0.2f
#define NSCANB 79            // ceil(NNODES/256)

typedef unsigned short u16;
typedef __attribute__((ext_vector_type(8))) short bf16x8;
typedef __attribute__((ext_vector_type(4))) float f32x4;

__device__ __forceinline__ float bf2f(u16 u) {
  return __uint_as_float(((unsigned int)u) << 16);
}
__device__ __forceinline__ u16 f2bf(float f) {
  unsigned int x = __float_as_uint(f);
  return (u16)((x + 0x7fffu + ((x >> 16) & 1u)) >> 16);
}
__device__ __forceinline__ float lrelu(float v) {
  return v >= 0.f ? v : NEG_SLOPE * v;
}
// async global->LDS, 16 B per lane; LDS dest must be wave-uniform base + lane*16
__device__ __forceinline__ void gl2lds16(const u16* g, u16* l) {
  __builtin_amdgcn_global_load_lds(
      (const __attribute__((address_space(1))) unsigned int*)g,
      (__attribute__((address_space(3))) unsigned int*)l, 16, 0, 0);
}
__device__ __forceinline__ float readlane_f(float v, int j) {
  return __uint_as_float(__builtin_amdgcn_readlane(__float_as_uint(v), j));
}

#define W1N (1024 * 128)
#define W2N (128 * 1024)
#define OWN (128 * 128)
#define EMB0N (NNODES * 128)
#define WSDN (16 * 128)      // 16 fused attention vectors (8 ws + 8 wd), 128-dim

// ---------------- fused: layer-0 embed + weight cvt + wsd precompute + edge counting --------
// wsd[vec][k] = sum_c att[h][c] * W1[h*128+c][k], vec = h (ws) or 8+h (wd)
__global__ void prep(const float* __restrict__ cons, const float* __restrict__ cols,
                     const float* __restrict__ nW, const float* __restrict__ nb,
                     const float* __restrict__ cW, const float* __restrict__ cb,
                     const float* __restrict__ W1, const float* __restrict__ W2,
                     const float* __restrict__ oW, const float* __restrict__ att_s1,
                     const float* __restrict__ att_d1, u16* __restrict__ emb,
                     u16* __restrict__ Wbf, u16* __restrict__ wsd,
                     const int* __restrict__ edges, int* __restrict__ counts) {
  int idx = blockIdx.x * 256 + threadIdx.x;
  if (idx < NETOT) {
    int dst = (idx < NEDGE) ? edges[NEDGE + idx] : (idx - NEDGE);
    atomicAdd(&counts[dst], 1);
  }
  if (idx < EMB0N) {
    int row = idx >> 7, o = idx & 127;
    float acc;
    if (row < NCONS) {
      acc = nb[o];
      #pragma unroll
      for (int k = 0; k < 4; ++k)
        acc += cons[row * 4 + k] * (nW[o * 8 + k] + nW[o * 8 + 4 + k]);
    } else {
      int r = row - NCONS;
      acc = cb[o];
      #pragma unroll
      for (int k = 0; k < 8; ++k)
        acc += cols[r * 8 + k] * (cW[o * 16 + k] + cW[o * 16 + 8 + k]);
    }
    emb[idx] = f2bf(fmaxf(acc, 0.f));
    return;
  }
  int i = idx - EMB0N;
  if (i < W1N + W2N + OWN) {
    float v;
    if (i < W1N) v = W1[i];
    else if (i < W1N + W2N) v = W2[i - W1N];
    else v = oW[i - W1N - W2N];
    Wbf[i] = f2bf(v);
    return;
  }
  int i2 = i - (W1N + W2N + OWN);
  if (i2 < WSDN) {
    int vec = i2 >> 7, k = i2 & 127;
    int h = vec & 7;
    const float* att = (vec < 8) ? att_s1 : att_d1;
    float a = 0.f;
    #pragma unroll 8
    for (int c = 0; c < 128; ++c)
      a += att[h * 128 + c] * W1[(size_t)(h * 128 + c) * 128 + k];
    wsd[i2] = f2bf(a);
  }
}

// ---------------- CSR build ----------------
__global__ void scan_a(const int* __restrict__ counts, int* __restrict__ lscan,
                       int* __restrict__ bsum) {
  __shared__ int sh[256];
  int t = threadIdx.x;
  int i = blockIdx.x * 256 + t;
  int v = (i < NNODES) ? counts[i] : 0;
  sh[t] = v;
  __syncthreads();
  for (int d = 1; d < 256; d <<= 1) {
    int add = (t >= d) ? sh[t - d] : 0;
    __syncthreads();
    sh[t] += add;
    __syncthreads();
  }
  lscan[i] = sh[t];
  if (t == 255) bsum[blockIdx.x] = sh[255];
}
// each block redundantly scans the 79 block sums in LDS, then emits offsets+cursor
__global__ void scan_c2(const int* __restrict__ lscan, const int* __restrict__ counts,
                        const int* __restrict__ bsum, int* __restrict__ offsets,
                        int* __restrict__ cursor) {
  __shared__ int sh[128];
  int t = threadIdx.x;
  if (t < 128) sh[t] = (t < NSCANB) ? bsum[t] : 0;
  __syncthreads();
  for (int d = 1; d < 128; d <<= 1) {
    int add = (t >= d && t < 128) ? sh[t - d] : 0;
    __syncthreads();
    if (t < 128) sh[t] += add;
    __syncthreads();
  }
  int bbase = (blockIdx.x > 0) ? sh[blockIdx.x - 1] : 0;
  int i = blockIdx.x * 256 + t;
  if (i == 0) offsets[0] = 0;
  if (i < NNODES) {
    int incl = lscan[i] + bbase;
    offsets[i + 1] = incl;
    cursor[i] = incl - counts[i];
  }
}

__global__ void fill_edges(const int* __restrict__ edges, int* __restrict__ cursor,
                           int* __restrict__ csr_src) {
  int i = blockIdx.x * 256 + threadIdx.x;
  if (i >= NETOT) return;
  int src, dst;
  if (i < NEDGE) { src = edges[i]; dst = edges[NEDGE + i]; }
  else { src = dst = i - NEDGE; }
  int pos = atomicAdd(&cursor[dst], 1);
  csr_src[pos] = src;
}

// ---------------- dots1: a_src/a_dst [N][8] = emb0 @ wsd^T via MFMA 16x16x32 ----------------
// 4 waves/block, wave = 16 nodes; 4 MFMAs over K=128. C cols 0..7 -> as, 8..15 -> ad.
__global__ __launch_bounds__(256) void dots1_k(const u16* __restrict__ emb,
                                               const u16* __restrict__ wsd,
                                               float* __restrict__ as1,
                                               float* __restrict__ ad1) {
  int wv = threadIdx.x >> 6, lane = threadIdx.x & 63;
  int quad = lane >> 4, l16 = lane & 15;
  int m0 = blockIdx.x * 64 + wv * 16;
  int ra = m0 + l16; if (ra >= NNODES) ra = NNODES - 1;
  f32x4 acc = f32x4{0.f, 0.f, 0.f, 0.f};
  #pragma unroll
  for (int k0 = 0; k0 < 128; k0 += 32) {
    bf16x8 a = *(const bf16x8*)(emb + (size_t)ra * 128 + k0 + quad * 8);
    bf16x8 b = *(const bf16x8*)(wsd + (size_t)l16 * 128 + k0 + quad * 8);
    acc = __builtin_amdgcn_mfma_f32_16x16x32_bf16(a, b, acc, 0, 0, 0);
  }
  #pragma unroll
  for (int r = 0; r < 4; ++r) {
    int node = m0 + quad * 4 + r;
    if (node < NNODES) {
      if (l16 < 8) as1[node * 8 + l16] = acc[r];
      else         ad1[node * 8 + (l16 - 8)] = acc[r];
    }
  }
}

// ---------------- LDS-staged GEMM: C[M,N] = A[M,K] @ B[N,K]^T ----------------
// BM x 128 block tile, BK=32, 256 thr = 4 waves. SLICED: per-head A/B slices selected by
// blockIdx.y (A += h*aSlice, B += h*128*K, B rows local). DOTS: attention-dot partials ->
// atomicAdd (h = blockIdx.y).
template <int BM, bool SLICED, bool DOTS, bool BIAS, bool RELU, bool OUTF32>
__global__ __launch_bounds__(256) void gemm_bt(const u16* __restrict__ A, const u16* __restrict__ B,
                                               const float* __restrict__ bias, void* __restrict__ Cv,
                                               const float* __restrict__ att_s,
                                               const float* __restrict__ att_d,
                                               float* __restrict__ a_srcO, float* __restrict__ a_dstO,
                                               int M, int N, int K, size_t aSlice) {
  constexpr int MI = BM / 32;
  __shared__ u16 sA[BM * 32];
  __shared__ u16 sB[128 * 32];
  int tid = threadIdx.x;
  int wv = tid >> 6;
  int lane = tid & 63;
  int quad = lane >> 4;
  int l16 = lane & 15;
  int m0 = blockIdx.x * BM;
  int n0g = blockIdx.y * 128;
  int h = n0g >> 7;
  const u16* Ab = SLICED ? A + (size_t)h * aSlice : A;
  const u16* Bb = SLICED ? B + (size_t)h * (size_t)128 * K : B;
  int brow0 = SLICED ? 0 : n0g;
  int rm = (wv >> 1) * (16 * MI);
  int cn = (wv & 1) * 64;

  f32x4 acc[MI][4];
  #pragma unroll
  for (int mi = 0; mi < MI; ++mi)
    #pragma unroll
    for (int ni = 0; ni < 4; ++ni) acc[mi][ni] = f32x4{0.f, 0.f, 0.f, 0.f};

  for (int k0 = 0; k0 < K; k0 += 32) {
    for (int off = tid * 16; off < BM * 64; off += 4096) {
      int row = off >> 6;
      int kk = (off & 63) >> 1;
      int rg = m0 + row; if (rg >= M) rg = M - 1;
      gl2lds16(Ab + (size_t)rg * K + k0 + kk, &sA[off >> 1]);
    }
    for (int off = tid * 16; off < 128 * 64; off += 4096) {
      int row = off >> 6;
      int kk = (off & 63) >> 1;
      gl2lds16(Bb + (size_t)(brow0 + row) * K + k0 + kk, &sB[off >> 1]);
    }
    __syncthreads();
    bf16x8 af[MI], bf[4];
    #pragma unroll
    for (int mi = 0; mi < MI; ++mi)
      af[mi] = *(const bf16x8*)&sA[(rm + mi * 16 + l16) * 32 + quad * 8];
    #pragma unroll
    for (int ni = 0; ni < 4; ++ni)
      bf[ni] = *(const bf16x8*)&sB[(cn + ni * 16 + l16) * 32 + quad * 8];
    #pragma unroll
    for (int mi = 0; mi < MI; ++mi)
      #pragma unroll
      for (int ni = 0; ni < 4; ++ni)
        acc[mi][ni] = __builtin_amdgcn_mfma_f32_16x16x32_bf16(af[mi], bf[ni], acc[mi][ni], 0, 0, 0);
    __syncthreads();
  }

  if (DOTS) {
    float av_s[4], av_d[4];
    #pragma unroll
    for (int ni = 0; ni < 4; ++ni) {
      int col = n0g + cn + ni * 16 + l16;
      av_s[ni] = att_s[col];
      av_d[ni] = att_d[col];
    }
    int H = N >> 7;
    #pragma unroll
    for (int mi = 0; mi < MI; ++mi) {
      #pragma unroll
      for (int r = 0; r < 4; ++r) {
        float sp = 0.f, dp = 0.f;
        #pragma unroll
        for (int ni = 0; ni < 4; ++ni) {
          sp += acc[mi][ni][r] * av_s[ni];
          dp += acc[mi][ni][r] * av_d[ni];
        }
        #pragma unroll
        for (int w = 1; w < 16; w <<= 1) {
          sp += __shfl_xor(sp, w, 64);
          dp += __shfl_xor(dp, w, 64);
        }
        int orow = m0 + rm + mi * 16 + quad * 4 + r;
        if (l16 == 0 && orow < M) {
          atomicAdd(&a_srcO[(size_t)orow * H + h], sp);
          atomicAdd(&a_dstO[(size_t)orow * H + h], dp);
        }
      }
    }
  }
  #pragma unroll
  for (int ni = 0; ni < 4; ++ni) {
    int col = n0g + cn + ni * 16 + l16;
    float bv = BIAS ? bias[col] : 0.f;
    #pragma unroll
    for (int mi = 0; mi < MI; ++mi) {
      #pragma unroll
      for (int r = 0; r < 4; ++r) {
        int orow = m0 + rm + mi * 16 + quad * 4 + r;
        if (orow < M) {
          float v = acc[mi][ni][r] + bv;
          if (RELU) v = fmaxf(v, 0.f);
          if (OUTF32) ((float*)Cv)[(size_t)orow * N + col] = v;
          else        ((u16*)Cv)[(size_t)orow * N + col] = f2bf(v);
        }
      }
    }
  }
}

// ---------------- alpha layer1 (H=8): edge-major out [NETOT][8] ----------------
// one wave per dst; lane = i*8+h. Gathers hoisted ahead of the softmax chain.
__global__ __launch_bounds__(256) void alpha1_k(const int* __restrict__ offs,
                                                const int* __restrict__ csr_src,
                                                const float* __restrict__ a_src,
                                                const float* __restrict__ a_dst,
                                                float* __restrict__ alpha) {
  int wv = threadIdx.x >> 6;
  int dst = blockIdx.x * 4 + wv;
  if (dst >= NNODES) return;
  int l = threadIdx.x & 63;
  int h = l & 7, i = l >> 3;
  int off = offs[dst];
  int deg = offs[dst + 1] - off;
  const int* srcs = csr_src + off;
  float ad = a_dst[dst * 8 + h];
  float m = -1e30f, ssum = 0.f;
  float* out = alpha + (size_t)off * 8;
  if (deg <= 64) {
    int sl = srcs[l < deg ? l : deg - 1];       // coalesced preload
    float g[8];
    #pragma unroll
    for (int t = 0; t < 8; ++t) {               // 8 independent gathers in flight
      int jj = i + t * 8;
      int s = __builtin_amdgcn_readlane(sl, jj < deg ? jj : 0);
      g[t] = a_src[s * 8 + h];                  // 8 h-lanes share s: 32-B segment
    }
    float ev[8];
    #pragma unroll
    for (int t = 0; t < 8; ++t) {
      int jj = i + t * 8;
      float e = (jj < deg) ? lrelu(g[t] + ad) : -1e30f;
      ev[t] = e;
      float nm = fmaxf(m, e);
      ssum = ssum * __expf(m - nm) + ((jj < deg) ? __expf(e - nm) : 0.f);
      m = nm;
    }
    #pragma unroll
    for (int w = 8; w < 64; w <<= 1) {          // reduce over i (lane bits 3..5)
      float om = __shfl_xor(m, w, 64);
      float os = __shfl_xor(ssum, w, 64);
      float nm = fmaxf(m, om);
      ssum = ssum * __expf(m - nm) + os * __expf(om - nm);
      m = nm;
    }
    float inv = 1.f / (ssum + 1e-16f);
    #pragma unroll
    for (int t = 0; t < 8; ++t) {
      int jj = i + t * 8;
      if (jj < deg) out[(size_t)jj * 8 + h] = __expf(ev[t] - m) * inv;
    }
  } else {
    for (int j = i; j < deg; j += 8) {
      int s = srcs[j];
      float e = lrelu(a_src[s * 8 + h] + ad);
      float nm = fmaxf(m, e);
      ssum = ssum * __expf(m - nm) + __expf(e - nm);
      m = nm;
    }
    #pragma unroll
    for (int w = 8; w < 64; w <<= 1) {
      float om = __shfl_xor(m, w, 64);
      float os = __shfl_xor(ssum, w, 64);
      float nm = fmaxf(m, om);
      ssum = ssum * __expf(m - nm) + os * __expf(om - nm);
      m = nm;
    }
    float inv = 1.f / (ssum + 1e-16f);
    for (int j = i; j < deg; j += 8) {
      int s = srcs[j];
      float e = lrelu(a_src[s * 8 + h] + ad);
      out[(size_t)j * 8 + h] = __expf(e - m) * inv;
    }
  }
}

// ---------------- magg1: multi-head aggregate agg^h = A_alpha^h @ emb0 ----------------
// wave per dst; gather each edge's 256-B emb0 row ONCE, apply all 8 heads' alpha.
// alpha edge-major [NETOT][8]: per 8-edge group one coalesced 256-B lane-linear load.
// Lane owns channels 2l,2l+1 for all 8 heads (acc[8][2]). Output head-major [8][N][128].
__global__ __launch_bounds__(256) void magg1(const int* __restrict__ offs,
                                             const int* __restrict__ csr_src,
                                             const float* __restrict__ alp,
                                             const u16* __restrict__ emb,
                                             u16* __restrict__ aggh) {
  int wvi = threadIdx.x >> 6;
  int dst = blockIdx.x * 4 + wvi;
  if (dst >= NNODES) return;
  int l = threadIdx.x & 63;
  int off = offs[dst];
  int deg = offs[dst + 1] - off;
  const int* srcs = csr_src + off;
  const u16* base = emb + l * 2;
  float acc[8][2];
  #pragma unroll
  for (int h = 0; h < 8; ++h) { acc[h][0] = 0.f; acc[h][1] = 0.f; }
  for (int b0 = 0; b0 < deg; b0 += 64) {
    int cnt = deg - b0; if (cnt > 64) cnt = 64;
    int sv = srcs[b0 + (l < cnt ? l : cnt - 1)];       // coalesced preload
    int g0 = 0;
    for (; g0 + 8 <= cnt; g0 += 8) {                   // full 8-edge groups, unrolled
      float av = alp[(size_t)(off + b0 + g0) * 8 + l]; // lane-linear 256-B alpha line
      ushort2 uu[8];
      #pragma unroll
      for (int t = 0; t < 8; ++t) {                    // 8 independent gathers in flight
        int s = __builtin_amdgcn_readlane(sv, g0 + t);
        uu[t] = *(const ushort2*)(base + (size_t)s * 128);
      }
      #pragma unroll
      for (int t = 0; t < 8; ++t) {
        float x0 = bf2f(uu[t].x), x1 = bf2f(uu[t].y);
        #pragma unroll
        for (int h = 0; h < 8; ++h) {
          float w = readlane_f(av, t * 8 + h);
          acc[h][0] += w * x0;
          acc[h][1] += w * x1;
        }
      }
    }
    if (g0 < cnt) {                                    // masked tail group
      int ei = g0 + (l >> 3);
      float av = (ei < cnt) ? alp[(size_t)(off + b0 + ei) * 8 + (l & 7)] : 0.f;
      int gn = cnt - g0;
      ushort2 uu[8];
      for (int t = 0; t < gn; ++t) {
        int s = __builtin_amdgcn_readlane(sv, g0 + t);
        uu[t] = *(const ushort2*)(base + (size_t)s * 128);
      }
      for (int t = 0; t < gn; ++t) {
        float x0 = bf2f(uu[t].x), x1 = bf2f(uu[t].y);
        #pragma unroll
        for (int h = 0; h < 8; ++h) {
          float w = readlane_f(av, t * 8 + h);
          acc[h][0] += w * x0;
          acc[h][1] += w * x1;
        }
      }
    }
  }
  #pragma unroll
  for (int h = 0; h < 8; ++h) {
    ushort2 o;
    o.x = f2bf(acc[h][0]);
    o.y = f2bf(acc[h][1]);
    *(ushort2*)(aggh + (size_t)h * ((size_t)NNODES * 128) + (size_t)dst * 128 + l * 2) = o;
  }
}

// ---------------- fused softmax + SpMM layer2 (H=1), dst in [NCONS, NNODES) ----------------
__global__ __launch_bounds__(256) void fsp2(const int* __restrict__ offs,
                                            const int* __restrict__ csr_src,
                                            const float* __restrict__ a_src,
                                            const float* __restrict__ a_dst,
                                            const u16* __restrict__ xp2,
                                            const float* __restrict__ bias,
                                            u16* __restrict__ out) {
  int wvi = threadIdx.x >> 6;
  int dst = NCONS + blockIdx.x * 4 + wvi;
  if (dst >= NNODES) return;
  int l = threadIdx.x & 63;
  int off = offs[dst];
  int deg = offs[dst + 1] - off;
  const int* srcs = csr_src + off;
  float ad = a_dst[dst];
  const u16* base = xp2 + l * 2;
  float m = -1e30f, ssum = 0.f, a0 = 0.f, a1 = 0.f;
  for (int b0 = 0; b0 < deg; b0 += 64) {
    int cnt = deg - b0; if (cnt > 64) cnt = 64;
    int sv = srcs[b0 + (l < cnt ? l : cnt - 1)];
    float e = (l < cnt) ? lrelu(a_src[sv] + ad) : -1e30f;
    float mc = e;
    #pragma unroll
    for (int w = 1; w < 64; w <<= 1) mc = fmaxf(mc, __shfl_xor(mc, w, 64));
    float pex = __expf(e - mc);
    float sc = pex;
    #pragma unroll
    for (int w = 1; w < 64; w <<= 1) sc += __shfl_xor(sc, w, 64);
    float c0 = 0.f, c1 = 0.f;
    int j = 0;
    for (; j + 8 <= cnt; j += 8) {
      ushort2 uu[8];
      float ww[8];
      #pragma unroll
      for (int t = 0; t < 8; ++t) {
        int s = __builtin_amdgcn_readlane(sv, j + t);
        ww[t] = readlane_f(pex, j + t);
        uu[t] = *(const ushort2*)(base + (size_t)s * 128);
      }
      #pragma unroll
      for (int t = 0; t < 8; ++t) {
        c0 += ww[t] * bf2f(uu[t].x);
        c1 += ww[t] * bf2f(uu[t].y);
      }
    }
    for (; j < cnt; ++j) {
      int s = __builtin_amdgcn_readlane(sv, j);
      float w = readlane_f(pex, j);
      ushort2 u = *(const ushort2*)(base + (size_t)s * 128);
      c0 += w * bf2f(u.x);
      c1 += w * bf2f(u.y);
    }
    float nm = fmaxf(m, mc);
    float fo = __expf(m - nm), fn = __expf(mc - nm);
    a0 = a0 * fo + c0 * fn;
    a1 = a1 * fo + c1 * fn;
    ssum = ssum * fo + sc * fn;
    m = nm;
  }
  float inv = 1.f / (ssum + 1e-16f);
  int cg = l * 2;
  ushort2 o;
  o.x = f2bf(fmaxf(a0 * inv + bias[cg], 0.f));
  o.y = f2bf(fmaxf(a1 * inv + bias[cg + 1], 0.f));
  *(ushort2*)(out + (size_t)dst * 128 + cg) = o;
}

// ---------------- launch ----------------
extern "C" void kernel_launch(void* const* d_in, const int* in_sizes, int n_in,
                              void* d_out, int out_size, void* d_ws, size_t ws_size,
                              hipStream_t stream) {
  const float* cons    = (const float*)d_in[0];
  const float* cols    = (const float*)d_in[1];
  const float* node_W  = (const float*)d_in[2];
  const float* node_b  = (const float*)d_in[3];
  const float* col_W   = (const float*)d_in[4];
  const float* col_b   = (const float*)d_in[5];
  const float* W1      = (const float*)d_in[6];
  const float* att_s1  = (const float*)d_in[7];
  const float* att_d1  = (const float*)d_in[8];
  const float* b1      = (const float*)d_in[9];
  const float* W2      = (const float*)d_in[10];
  const float* att_s2  = (const float*)d_in[11];
  const float* att_d2  = (const float*)d_in[12];
  const float* b2      = (const float*)d_in[13];
  const float* out_W   = (const float*)d_in[14];
  const float* out_b   = (const float*)d_in[15];
  const int* edges     = (const int*)d_in[16];

  char* p = (char*)d_ws;
  auto alloc = [&](size_t bytes) {
    char* r = p;
    p += (bytes + 255) & ~(size_t)255;
    return r;
  };
  u16* emb0    = (u16*)alloc((size_t)NNODES * 128 * 2);        // bf16
  u16* aggh    = (u16*)alloc((size_t)8 * NNODES * 128 * 2);    // bf16, head-major agg slices
  u16* emb2    = (u16*)alloc((size_t)NNODES * 1024 * 2);       // bf16
  u16* xp2     = (u16*)alloc((size_t)NNODES * 128 * 2);        // bf16
  u16* emb3    = (u16*)alloc((size_t)NNODES * 128 * 2);        // bf16
  u16* Wbf     = (u16*)alloc((size_t)(W1N + W2N + OWN) * 2);   // W1|W2|out_W contiguous
  u16* wsd     = (u16*)alloc((size_t)WSDN * 2);                // fused att vectors bf16
  // ---- contiguous zero region: as2, ad2, counts ----
  float* as2   = (float*)alloc((size_t)NNODES * 4);            // pads to 80128 B
  float* ad2   = (float*)alloc((size_t)NNODES * 4);            // pads to 80128 B
  int* counts  = (int*)alloc((size_t)NNODES * 4);              // pads to 80128 B
  size_t zspan = (char*)(counts + NNODES) - (char*)as2;
  // ---- end zero region ----
  float* as1   = (float*)alloc((size_t)NNODES * 8 * 4);
  float* ad1   = (float*)alloc((size_t)NNODES * 8 * 4);
  float* alp1  = (float*)alloc((size_t)NETOT * 8 * 4);         // edge-major [NETOT][8]
  int* offs    = (int*)alloc((size_t)(NNODES + 1) * 4);
  int* cursor  = (int*)alloc((size_t)NNODES * 4);
  int* csrsrc  = (int*)alloc((size_t)NETOT * 4);
  int* lscan   = (int*)alloc((size_t)NSCANB * 256 * 4);
  int* bsum    = (int*)alloc((size_t)NSCANB * 4);

  u16* W1bf = Wbf;
  u16* W2bf = Wbf + W1N;
  u16* oWbf = Wbf + W1N + W2N;

  hipMemsetAsync(as2, 0, zspan, stream);

  // layer-0 embed + weight cvt + wsd + edge counting (fused)
  prep<<<(EMB0N + W1N + W2N + OWN + WSDN + 255) / 256, 256, 0, stream>>>(
      cons, cols, node_W, node_b, col_W, col_b, W1, W2, out_W, att_s1, att_d1,
      emb0, Wbf, wsd, edges, counts);

  // CSR build
  scan_a<<<NSCANB, 256, 0, stream>>>(counts, lscan, bsum);
  scan_c2<<<NSCANB, 256, 0, stream>>>(lscan, counts, bsum, offs, cursor);
  fill_edges<<<(NETOT + 255) / 256, 256, 0, stream>>>(edges, cursor, csrsrc);

  // GAT layer 1 (aggregate-then-transform):
  // dots via micro-GEMM -> alpha (edge-major) -> multi-head aggregate -> per-head GEMM
  dots1_k<<<(NNODES + 63) / 64, 256, 0, stream>>>(emb0, wsd, as1, ad1);
  alpha1_k<<<(NNODES + 3) / 4, 256, 0, stream>>>(offs, csrsrc, as1, ad1, alp1);
  magg1<<<(NNODES + 3) / 4, 256, 0, stream>>>(offs, csrsrc, alp1, emb0, aggh);
  gemm_bt<128, true, false, true, true, false><<<dim3((NNODES + 127) / 128, 8), 256, 0, stream>>>(
      aggh, W1bf, b1, emb2, nullptr, nullptr, nullptr, nullptr,
      NNODES, 1024, 128, (size_t)NNODES * 128);

  // GAT layer 2 (transform-then-aggregate): GEMM (fused dots) -> fused softmax+SpMM
  gemm_bt<32, false, true, false, false, false><<<dim3((NNODES + 31) / 32, 1), 256, 0, stream>>>(
      emb2, W2bf, nullptr, xp2, att_s2, att_d2, as2, ad2, NNODES, 128, 1024, 0);
  fsp2<<<(NCOLSN + 3) / 4, 256, 0, stream>>>(offs, csrsrc, as2, ad2, xp2, b2, emb3);

  // output projection: rows 10000..19999, f32 out with bias
  gemm_bt<32, false, false, true, false, true><<<dim3((NCOLSN + 31) / 32, 1), 256, 0, stream>>>(
      emb3 + (size_t)NCONS * 128, oWbf, out_b, d_out, nullptr, nullptr, nullptr, nullptr,
      NCOLSN, 128, 128, 0);
}

// Round 15
// 244.231 us; speedup vs baseline: 1.3796x; 1.0725x over previous
//
#include <hip/hip_runtime.h>

// ---------------- problem constants ----------------
#define NCONS 10000
#define NCOLSN 10000
#define NNODES 20000         // NCONS + NCOLSN
#define NEDGE 200000
#define NETOT 220000         // NEDGE + NNODES self loops
#define NEG_SLOPE 0.2f
#define NSCANB 79            // ceil(NNODES/256)

typedef unsigned short u16;
typedef __attribute__((ext_vector_type(8))) short bf16x8;
typedef __attribute__((ext_vector_type(4))) float f32x4;

__device__ __forceinline__ float bf2f(u16 u) {
  return __uint_as_float(((unsigned int)u) << 16);
}
__device__ __forceinline__ u16 f2bf(float f) {
  unsigned int x = __float_as_uint(f);
  return (u16)((x + 0x7fffu + ((x >> 16) & 1u)) >> 16);
}
__device__ __forceinline__ float lrelu(float v) {
  return v >= 0.f ? v : NEG_SLOPE * v;
}
// async global->LDS, 16 B per lane; LDS dest must be wave-uniform base + lane*16
__device__ __forceinline__ void gl2lds16(const u16* g, u16* l) {
  __builtin_amdgcn_global_load_lds(
      (const __attribute__((address_space(1))) unsigned int*)g,
      (__attribute__((address_space(3))) unsigned int*)l, 16, 0, 0);
}
__device__ __forceinline__ float readlane_f(float v, int j) {
  return __uint_as_float(__builtin_amdgcn_readlane(__float_as_uint(v), j));
}

#define W1N (1024 * 128)
#define W2N (128 * 1024)
#define OWN (128 * 128)
#define EMB0N (NNODES * 128)
#define WSDN (16 * 128)      // 16 fused attention vectors (8 ws + 8 wd), 128-dim

// ---------------- fused: layer-0 embed + weight cvt + wsd precompute + edge counting --------
// wsd[vec][k] = sum_c att[h][c] * W1[h*128+c][k], vec = h (ws) or 8+h (wd)
__global__ void prep(const float* __restrict__ cons, const float* __restrict__ cols,
                     const float* __restrict__ nW, const float* __restrict__ nb,
                     const float* __restrict__ cW, const float* __restrict__ cb,
                     const float* __restrict__ W1, const float* __restrict__ W2,
                     const float* __restrict__ oW, const float* __restrict__ att_s1,
                     const float* __restrict__ att_d1, u16* __restrict__ emb,
                     u16* __restrict__ Wbf, u16* __restrict__ wsd,
                     const int* __restrict__ edges, int* __restrict__ counts) {
  int idx = blockIdx.x * 256 + threadIdx.x;
  if (idx < NETOT) {
    int dst = (idx < NEDGE) ? edges[NEDGE + idx] : (idx - NEDGE);
    atomicAdd(&counts[dst], 1);
  }
  if (idx < EMB0N) {
    int row = idx >> 7, o = idx & 127;
    float acc;
    if (row < NCONS) {
      acc = nb[o];
      #pragma unroll
      for (int k = 0; k < 4; ++k)
        acc += cons[row * 4 + k] * (nW[o * 8 + k] + nW[o * 8 + 4 + k]);
    } else {
      int r = row - NCONS;
      acc = cb[o];
      #pragma unroll
      for (int k = 0; k < 8; ++k)
        acc += cols[r * 8 + k] * (cW[o * 16 + k] + cW[o * 16 + 8 + k]);
    }
    emb[idx] = f2bf(fmaxf(acc, 0.f));
    return;
  }
  int i = idx - EMB0N;
  if (i < W1N + W2N + OWN) {
    float v;
    if (i < W1N) v = W1[i];
    else if (i < W1N + W2N) v = W2[i - W1N];
    else v = oW[i - W1N - W2N];
    Wbf[i] = f2bf(v);
    return;
  }
  int i2 = i - (W1N + W2N + OWN);
  if (i2 < WSDN) {
    int vec = i2 >> 7, k = i2 & 127;
    int h = vec & 7;
    const float* att = (vec < 8) ? att_s1 : att_d1;
    float a = 0.f;
    #pragma unroll 8
    for (int c = 0; c < 128; ++c)
      a += att[h * 128 + c] * W1[(size_t)(h * 128 + c) * 128 + k];
    wsd[i2] = f2bf(a);
  }
}

// ---------------- CSR build ----------------
__global__ void scan_a(const int* __restrict__ counts, int* __restrict__ lscan,
                       int* __restrict__ bsum) {
  __shared__ int sh[256];
  int t = threadIdx.x;
  int i = blockIdx.x * 256 + t;
  int v = (i < NNODES) ? counts[i] : 0;
  sh[t] = v;
  __syncthreads();
  for (int d = 1; d < 256; d <<= 1) {
    int add = (t >= d) ? sh[t - d] : 0;
    __syncthreads();
    sh[t] += add;
    __syncthreads();
  }
  lscan[i] = sh[t];
  if (t == 255) bsum[blockIdx.x] = sh[255];
}
__global__ void scan_c2(const int* __restrict__ lscan, const int* __restrict__ counts,
                        const int* __restrict__ bsum, int* __restrict__ offsets,
                        int* __restrict__ cursor) {
  __shared__ int sh[128];
  int t = threadIdx.x;
  if (t < 128) sh[t] = (t < NSCANB) ? bsum[t] : 0;
  __syncthreads();
  for (int d = 1; d < 128; d <<= 1) {
    int add = (t >= d && t < 128) ? sh[t - d] : 0;
    __syncthreads();
    if (t < 128) sh[t] += add;
    __syncthreads();
  }
  int bbase = (blockIdx.x > 0) ? sh[blockIdx.x - 1] : 0;
  int i = blockIdx.x * 256 + t;
  if (i == 0) offsets[0] = 0;
  if (i < NNODES) {
    int incl = lscan[i] + bbase;
    offsets[i + 1] = incl;
    cursor[i] = incl - counts[i];
  }
}

__global__ void fill_edges(const int* __restrict__ edges, int* __restrict__ cursor,
                           int* __restrict__ csr_src) {
  int i = blockIdx.x * 256 + threadIdx.x;
  if (i >= NETOT) return;
  int src, dst;
  if (i < NEDGE) { src = edges[i]; dst = edges[NEDGE + i]; }
  else { src = dst = i - NEDGE; }
  int pos = atomicAdd(&cursor[dst], 1);
  csr_src[pos] = src;
}

// ---------------- dots1: a_src/a_dst [N][8] = emb0 @ wsd^T via MFMA 16x16x32 ----------------
__global__ __launch_bounds__(256) void dots1_k(const u16* __restrict__ emb,
                                               const u16* __restrict__ wsd,
                                               float* __restrict__ as1,
                                               float* __restrict__ ad1) {
  int wv = threadIdx.x >> 6, lane = threadIdx.x & 63;
  int quad = lane >> 4, l16 = lane & 15;
  int m0 = blockIdx.x * 64 + wv * 16;
  int ra = m0 + l16; if (ra >= NNODES) ra = NNODES - 1;
  f32x4 acc = f32x4{0.f, 0.f, 0.f, 0.f};
  #pragma unroll
  for (int k0 = 0; k0 < 128; k0 += 32) {
    bf16x8 a = *(const bf16x8*)(emb + (size_t)ra * 128 + k0 + quad * 8);
    bf16x8 b = *(const bf16x8*)(wsd + (size_t)l16 * 128 + k0 + quad * 8);
    acc = __builtin_amdgcn_mfma_f32_16x16x32_bf16(a, b, acc, 0, 0, 0);
  }
  #pragma unroll
  for (int r = 0; r < 4; ++r) {
    int node = m0 + quad * 4 + r;
    if (node < NNODES) {
      if (l16 < 8) as1[node * 8 + l16] = acc[r];
      else         ad1[node * 8 + (l16 - 8)] = acc[r];
    }
  }
}

// ---------------- LDS-staged GEMM: C[M,N] = A[M,K] @ B[N,K]^T (row stride lda) -------------
// BM x 128 block tile, BK=32, 256 thr = 4 waves. SLICED: A += h*aOff (col offset into
// node-major A), B += h*128*K (per-head W rows, local). DOTS: attention-dot partials.
template <int BM, bool SLICED, bool DOTS, bool BIAS, bool RELU, bool OUTF32>
__global__ __launch_bounds__(256) void gemm_bt(const u16* __restrict__ A, const u16* __restrict__ B,
                                               const float* __restrict__ bias, void* __restrict__ Cv,
                                               const float* __restrict__ att_s,
                                               const float* __restrict__ att_d,
                                               float* __restrict__ a_srcO, float* __restrict__ a_dstO,
                                               int M, int N, int K, int lda, size_t aOff) {
  constexpr int MI = BM / 32;
  __shared__ u16 sA[BM * 32];
  __shared__ u16 sB[128 * 32];
  int tid = threadIdx.x;
  int wv = tid >> 6;
  int lane = tid & 63;
  int quad = lane >> 4;
  int l16 = lane & 15;
  int m0 = blockIdx.x * BM;
  int n0g = blockIdx.y * 128;
  int h = n0g >> 7;
  const u16* Ab = SLICED ? A + (size_t)h * aOff : A;
  const u16* Bb = SLICED ? B + (size_t)h * (size_t)128 * K : B;
  int brow0 = SLICED ? 0 : n0g;
  int rm = (wv >> 1) * (16 * MI);
  int cn = (wv & 1) * 64;

  f32x4 acc[MI][4];
  #pragma unroll
  for (int mi = 0; mi < MI; ++mi)
    #pragma unroll
    for (int ni = 0; ni < 4; ++ni) acc[mi][ni] = f32x4{0.f, 0.f, 0.f, 0.f};

  for (int k0 = 0; k0 < K; k0 += 32) {
    for (int off = tid * 16; off < BM * 64; off += 4096) {
      int row = off >> 6;
      int kk = (off & 63) >> 1;
      int rg = m0 + row; if (rg >= M) rg = M - 1;
      gl2lds16(Ab + (size_t)rg * lda + k0 + kk, &sA[off >> 1]);
    }
    for (int off = tid * 16; off < 128 * 64; off += 4096) {
      int row = off >> 6;
      int kk = (off & 63) >> 1;
      gl2lds16(Bb + (size_t)(brow0 + row) * K + k0 + kk, &sB[off >> 1]);
    }
    __syncthreads();
    bf16x8 af[MI], bf[4];
    #pragma unroll
    for (int mi = 0; mi < MI; ++mi)
      af[mi] = *(const bf16x8*)&sA[(rm + mi * 16 + l16) * 32 + quad * 8];
    #pragma unroll
    for (int ni = 0; ni < 4; ++ni)
      bf[ni] = *(const bf16x8*)&sB[(cn + ni * 16 + l16) * 32 + quad * 8];
    #pragma unroll
    for (int mi = 0; mi < MI; ++mi)
      #pragma unroll
      for (int ni = 0; ni < 4; ++ni)
        acc[mi][ni] = __builtin_amdgcn_mfma_f32_16x16x32_bf16(af[mi], bf[ni], acc[mi][ni], 0, 0, 0);
    __syncthreads();
  }

  if (DOTS) {
    float av_s[4], av_d[4];
    #pragma unroll
    for (int ni = 0; ni < 4; ++ni) {
      int col = n0g + cn + ni * 16 + l16;
      av_s[ni] = att_s[col];
      av_d[ni] = att_d[col];
    }
    int H = N >> 7;
    #pragma unroll
    for (int mi = 0; mi < MI; ++mi) {
      #pragma unroll
      for (int r = 0; r < 4; ++r) {
        float sp = 0.f, dp = 0.f;
        #pragma unroll
        for (int ni = 0; ni < 4; ++ni) {
          sp += acc[mi][ni][r] * av_s[ni];
          dp += acc[mi][ni][r] * av_d[ni];
        }
        #pragma unroll
        for (int w = 1; w < 16; w <<= 1) {
          sp += __shfl_xor(sp, w, 64);
          dp += __shfl_xor(dp, w, 64);
        }
        int orow = m0 + rm + mi * 16 + quad * 4 + r;
        if (l16 == 0 && orow < M) {
          atomicAdd(&a_srcO[(size_t)orow * H + h], sp);
          atomicAdd(&a_dstO[(size_t)orow * H + h], dp);
        }
      }
    }
  }
  #pragma unroll
  for (int ni = 0; ni < 4; ++ni) {
    int col = n0g + cn + ni * 16 + l16;
    float bv = BIAS ? bias[col] : 0.f;
    #pragma unroll
    for (int mi = 0; mi < MI; ++mi) {
      #pragma unroll
      for (int r = 0; r < 4; ++r) {
        int orow = m0 + rm + mi * 16 + quad * 4 + r;
        if (orow < M) {
          float v = acc[mi][ni][r] + bv;
          if (RELU) v = fmaxf(v, 0.f);
          if (OUTF32) ((float*)Cv)[(size_t)orow * N + col] = v;
          else        ((u16*)Cv)[(size_t)orow * N + col] = f2bf(v);
        }
      }
    }
  }
}

// ---------------- fagg1: fused softmax + multi-head aggregate, agg = A_alpha @ emb0 --------
// wave per dst; lane = (i=l>>3, h=l&7) for softmax; alpha staged in per-wave LDS tile
// (write t*64+l: 2-way free; reads broadcast: free). Aggregation: 8-edge groups, clamped
// readlane slots (slot<=63 for deg<=64), zero-padded weights. Output node-major [N][1024].
__global__ __launch_bounds__(256) void fagg1(const int* __restrict__ offs,
                                             const int* __restrict__ csr_src,
                                             const float* __restrict__ as1,
                                             const float* __restrict__ ad1,
                                             const u16* __restrict__ emb,
                                             u16* __restrict__ agg) {
  __shared__ float alds[4 * 512];
  int wvi = threadIdx.x >> 6;
  int dst = blockIdx.x * 4 + wvi;
  if (dst >= NNODES) return;
  int l = threadIdx.x & 63;
  int h = l & 7, i = l >> 3;
  float* wlds = &alds[wvi * 512];
  int off = offs[dst];
  int deg = offs[dst + 1] - off;
  const int* srcs = csr_src + off;
  float adv = ad1[dst * 8 + h];
  const u16* base = emb + l * 2;
  float acc[8][2];
  #pragma unroll
  for (int hh = 0; hh < 8; ++hh) { acc[hh][0] = 0.f; acc[hh][1] = 0.f; }

  if (deg <= 64) {
    int sl = srcs[l < deg ? l : deg - 1];         // coalesced preload
    float g[8];
    #pragma unroll
    for (int t = 0; t < 8; ++t) {                 // 8 independent a_src gathers in flight
      int jj = t * 8 + i;
      int s = __builtin_amdgcn_readlane(sl, jj < deg ? jj : 0);
      g[t] = as1[s * 8 + h];                      // 8 h-lanes share s: 32-B segment
    }
    float m = -1e30f, ssum = 0.f, ev[8];
    #pragma unroll
    for (int t = 0; t < 8; ++t) {
      int jj = t * 8 + i;
      float e = (jj < deg) ? lrelu(g[t] + adv) : -1e30f;
      ev[t] = e;
      float nm = fmaxf(m, e);
      ssum = ssum * __expf(m - nm) + ((jj < deg) ? __expf(e - nm) : 0.f);
      m = nm;
    }
    #pragma unroll
    for (int w = 8; w < 64; w <<= 1) {            // reduce over i (lane bits 3..5)
      float om = __shfl_xor(m, w, 64);
      float os = __shfl_xor(ssum, w, 64);
      float nm = fmaxf(m, om);
      ssum = ssum * __expf(m - nm) + os * __expf(om - nm);
      m = nm;
    }
    float inv = 1.f / (ssum + 1e-16f);
    #pragma unroll
    for (int t = 0; t < 8; ++t)                   // alpha -> LDS (edge t*8+i, head h)
      wlds[t * 64 + l] = __expf(ev[t] - m) * inv; // zero for invalid edges
    for (int j0 = 0; j0 < deg; j0 += 8) {
      ushort2 uu[8];
      #pragma unroll
      for (int t2 = 0; t2 < 8; ++t2) {            // 8 independent row gathers in flight
        int slot = j0 + t2;
        int s = __builtin_amdgcn_readlane(sl, slot < deg ? slot : 0);
        uu[t2] = *(const ushort2*)(base + (size_t)s * 128);
      }
      #pragma unroll
      for (int t2 = 0; t2 < 8; ++t2) {
        int slot = j0 + t2;                       // <= 63 (j0 <= 56 for deg <= 64)
        float x0 = bf2f(uu[t2].x), x1 = bf2f(uu[t2].y);
        #pragma unroll
        for (int hh = 0; hh < 8; ++hh) {
          float w = wlds[slot * 8 + hh];          // broadcast read, 0 beyond deg
          acc[hh][0] += w * x0;
          acc[hh][1] += w * x1;
        }
      }
    }
  } else {
    // rare slow path: streaming softmax, then chunked aggregate
    float m = -1e30f, ssum = 0.f;
    for (int j = i; j < deg; j += 8) {
      int s = srcs[j];
      float e = lrelu(as1[s * 8 + h] + adv);
      float nm = fmaxf(m, e);
      ssum = ssum * __expf(m - nm) + __expf(e - nm);
      m = nm;
    }
    #pragma unroll
    for (int w = 8; w < 64; w <<= 1) {
      float om = __shfl_xor(m, w, 64);
      float os = __shfl_xor(ssum, w, 64);
      float nm = fmaxf(m, om);
      ssum = ssum * __expf(m - nm) + os * __expf(om - nm);
      m = nm;
    }
    float inv = 1.f / (ssum + 1e-16f);
    for (int b0 = 0; b0 < deg; b0 += 64) {
      int cnt = deg - b0; if (cnt > 64) cnt = 64;
      #pragma unroll
      for (int t = 0; t < 8; ++t) {
        int sl2 = t * 8 + i;
        float a = 0.f;
        if (sl2 < cnt) {
          int s = srcs[b0 + sl2];
          a = __expf(lrelu(as1[s * 8 + h] + adv) - m) * inv;
        }
        wlds[t * 64 + l] = a;
      }
      int sv = srcs[b0 + (l < cnt ? l : cnt - 1)];
      for (int j0 = 0; j0 < cnt; j0 += 8) {
        ushort2 uu[8];
        #pragma unroll
        for (int t2 = 0; t2 < 8; ++t2) {
          int slot = j0 + t2;
          int s = __builtin_amdgcn_readlane(sv, slot < cnt ? slot : 0);
          uu[t2] = *(const ushort2*)(base + (size_t)s * 128);
        }
        #pragma unroll
        for (int t2 = 0; t2 < 8; ++t2) {
          int slot = j0 + t2;
          float x0 = bf2f(uu[t2].x), x1 = bf2f(uu[t2].y);
          #pragma unroll
          for (int hh = 0; hh < 8; ++hh) {
            float w = wlds[slot * 8 + hh];
            acc[hh][0] += w * x0;
            acc[hh][1] += w * x1;
          }
        }
      }
    }
  }
  #pragma unroll
  for (int hh = 0; hh < 8; ++hh) {
    ushort2 o;
    o.x = f2bf(acc[hh][0]);
    o.y = f2bf(acc[hh][1]);
    *(ushort2*)(agg + (size_t)dst * 1024 + hh * 128 + l * 2) = o;
  }
}

// ---------------- fused softmax + SpMM layer2 (H=1), dst in [NCONS, NNODES) ----------------
__global__ __launch_bounds__(256) void fsp2(const int* __restrict__ offs,
                                            const int* __restrict__ csr_src,
                                            const float* __restrict__ a_src,
                                            const float* __restrict__ a_dst,
                                            const u16* __restrict__ xp2,
                                            const float* __restrict__ bias,
                                            u16* __restrict__ out) {
  int wvi = threadIdx.x >> 6;
  int dst = NCONS + blockIdx.x * 4 + wvi;
  if (dst >= NNODES) return;
  int l = threadIdx.x & 63;
  int off = offs[dst];
  int deg = offs[dst + 1] - off;
  const int* srcs = csr_src + off;
  float ad = a_dst[dst];
  const u16* base = xp2 + l * 2;
  float m = -1e30f, ssum = 0.f, a0 = 0.f, a1 = 0.f;
  for (int b0 = 0; b0 < deg; b0 += 64) {
    int cnt = deg - b0; if (cnt > 64) cnt = 64;
    int sv = srcs[b0 + (l < cnt ? l : cnt - 1)];
    float e = (l < cnt) ? lrelu(a_src[sv] + ad) : -1e30f;
    float mc = e;
    #pragma unroll
    for (int w = 1; w < 64; w <<= 1) mc = fmaxf(mc, __shfl_xor(mc, w, 64));
    float pex = __expf(e - mc);
    float sc = pex;
    #pragma unroll
    for (int w = 1; w < 64; w <<= 1) sc += __shfl_xor(sc, w, 64);
    float c0 = 0.f, c1 = 0.f;
    int j = 0;
    for (; j + 8 <= cnt; j += 8) {
      ushort2 uu[8];
      float ww[8];
      #pragma unroll
      for (int t = 0; t < 8; ++t) {
        int s = __builtin_amdgcn_readlane(sv, j + t);
        ww[t] = readlane_f(pex, j + t);
        uu[t] = *(const ushort2*)(base + (size_t)s * 128);
      }
      #pragma unroll
      for (int t = 0; t < 8; ++t) {
        c0 += ww[t] * bf2f(uu[t].x);
        c1 += ww[t] * bf2f(uu[t].y);
      }
    }
    for (; j < cnt; ++j) {
      int s = __builtin_amdgcn_readlane(sv, j);
      float w = readlane_f(pex, j);
      ushort2 u = *(const ushort2*)(base + (size_t)s * 128);
      c0 += w * bf2f(u.x);
      c1 += w * bf2f(u.y);
    }
    float nm = fmaxf(m, mc);
    float fo = __expf(m - nm), fn = __expf(mc - nm);
    a0 = a0 * fo + c0 * fn;
    a1 = a1 * fo + c1 * fn;
    ssum = ssum * fo + sc * fn;
    m = nm;
  }
  float inv = 1.f / (ssum + 1e-16f);
  int cg = l * 2;
  ushort2 o;
  o.x = f2bf(fmaxf(a0 * inv + bias[cg], 0.f));
  o.y = f2bf(fmaxf(a1 * inv + bias[cg + 1], 0.f));
  *(ushort2*)(out + (size_t)dst * 128 + cg) = o;
}

// ---------------- launch ----------------
extern "C" void kernel_launch(void* const* d_in, const int* in_sizes, int n_in,
                              void* d_out, int out_size, void* d_ws, size_t ws_size,
                              hipStream_t stream) {
  const float* cons    = (const float*)d_in[0];
  const float* cols    = (const float*)d_in[1];
  const float* node_W  = (const float*)d_in[2];
  const float* node_b  = (const float*)d_in[3];
  const float* col_W   = (const float*)d_in[4];
  const float* col_b   = (const float*)d_in[5];
  const float* W1      = (const float*)d_in[6];
  const float* att_s1  = (const float*)d_in[7];
  const float* att_d1  = (const float*)d_in[8];
  const float* b1      = (const float*)d_in[9];
  const float* W2      = (const float*)d_in[10];
  const float* att_s2  = (const float*)d_in[11];
  const float* att_d2  = (const float*)d_in[12];
  const float* b2      = (const float*)d_in[13];
  const float* out_W   = (const float*)d_in[14];
  const float* out_b   = (const float*)d_in[15];
  const int* edges     = (const int*)d_in[16];

  char* p = (char*)d_ws;
  auto alloc = [&](size_t bytes) {
    char* r = p;
    p += (bytes + 255) & ~(size_t)255;
    return r;
  };
  u16* emb0    = (u16*)alloc((size_t)NNODES * 128 * 2);        // bf16
  u16* agg     = (u16*)alloc((size_t)NNODES * 1024 * 2);       // bf16, node-major [N][8*128]
  u16* emb2    = (u16*)alloc((size_t)NNODES * 1024 * 2);       // bf16
  u16* xp2     = (u16*)alloc((size_t)NNODES * 128 * 2);        // bf16
  u16* emb3    = (u16*)alloc((size_t)NNODES * 128 * 2);        // bf16
  u16* Wbf     = (u16*)alloc((size_t)(W1N + W2N + OWN) * 2);   // W1|W2|out_W contiguous
  u16* wsd     = (u16*)alloc((size_t)WSDN * 2);                // fused att vectors bf16
  // ---- contiguous zero region: as2, ad2, counts ----
  float* as2   = (float*)alloc((size_t)NNODES * 4);            // pads to 80128 B
  float* ad2   = (float*)alloc((size_t)NNODES * 4);            // pads to 80128 B
  int* counts  = (int*)alloc((size_t)NNODES * 4);              // pads to 80128 B
  size_t zspan = (char*)(counts + NNODES) - (char*)as2;
  // ---- end zero region ----
  float* as1   = (float*)alloc((size_t)NNODES * 8 * 4);
  float* ad1   = (float*)alloc((size_t)NNODES * 8 * 4);
  int* offs    = (int*)alloc((size_t)(NNODES + 1) * 4);
  int* cursor  = (int*)alloc((size_t)NNODES * 4);
  int* csrsrc  = (int*)alloc((size_t)NETOT * 4);
  int* lscan   = (int*)alloc((size_t)NSCANB * 256 * 4);
  int* bsum    = (int*)alloc((size_t)NSCANB * 4);

  u16* W1bf = Wbf;
  u16* W2bf = Wbf + W1N;
  u16* oWbf = Wbf + W1N + W2N;

  hipMemsetAsync(as2, 0, zspan, stream);

  // layer-0 embed + weight cvt + wsd + edge counting (fused)
  prep<<<(EMB0N + W1N + W2N + OWN + WSDN + 255) / 256, 256, 0, stream>>>(
      cons, cols, node_W, node_b, col_W, col_b, W1, W2, out_W, att_s1, att_d1,
      emb0, Wbf, wsd, edges, counts);

  // CSR build
  scan_a<<<NSCANB, 256, 0, stream>>>(counts, lscan, bsum);
  scan_c2<<<NSCANB, 256, 0, stream>>>(lscan, counts, bsum, offs, cursor);
  fill_edges<<<(NETOT + 255) / 256, 256, 0, stream>>>(edges, cursor, csrsrc);

  // GAT layer 1 (aggregate-then-transform):
  // dots micro-GEMM -> fused softmax+aggregate -> per-head GEMM (+bias+relu)
  dots1_k<<<(NNODES + 63) / 64, 256, 0, stream>>>(emb0, wsd, as1, ad1);
  fagg1<<<(NNODES + 3) / 4, 256, 0, stream>>>(offs, csrsrc, as1, ad1, emb0, agg);
  gemm_bt<128, true, false, true, true, false><<<dim3((NNODES + 127) / 128, 8), 256, 0, stream>>>(
      agg, W1bf, b1, emb2, nullptr, nullptr, nullptr, nullptr,
      NNODES, 1024, 128, 1024, 128);

  // GAT layer 2 (transform-then-aggregate): GEMM (fused dots) -> fused softmax+SpMM
  gemm_bt<32, false, true, false, false, false><<<dim3((NNODES + 31) / 32, 1), 256, 0, stream>>>(
      emb2, W2bf, nullptr, xp2, att_s2, att_d2, as2, ad2, NNODES, 128, 1024, 1024, 0);
  fsp2<<<(NCOLSN + 3) / 4, 256, 0, stream>>>(offs, csrsrc, as2, ad2, xp2, b2, emb3);

  // output projection: rows 10000..19999, f32 out with bias
  gemm_bt<32, false, false, true, false, true><<<dim3((NCOLSN + 31) / 32, 1), 256, 0, stream>>>(
      emb3 + (size_t)NCONS * 128, oWbf, out_b, d_out, nullptr, nullptr, nullptr, nullptr,
      NCOLSN, 128, 128, 128, 0);
}